// Round 12
// baseline (731.009 us; speedup 1.0000x reference)
//
#include <hip/hip_runtime.h>
#include <math.h>

// Problem constants
constexpr int kBS   = 16;
constexpr int kL    = 50;
constexpr int kNB   = 64;
constexpr int kD    = 256;
constexpr int kNBLK = 65536;
constexpr int kMaxUsed = 51200;          // 16*50*64 worst-case unique ids

#define NEG_HUGE (-3.402823466e38f)

typedef _Float16 h8 __attribute__((ext_vector_type(8)));
typedef float f32x4 __attribute__((ext_vector_type(4)));

// ---------------- helpers ----------------
__device__ __forceinline__ unsigned f2sort(float f) {
    unsigned u = __float_as_uint(f);
    return (u & 0x80000000u) ? ~u : (u | 0x80000000u);   // monotone ascending map
}

__device__ __forceinline__ void bitonic_u64(unsigned long long* s, int i, int n) {
    for (int k = 2; k <= n; k <<= 1) {
        for (int j = k >> 1; j > 0; j >>= 1) {
            __syncthreads();
            int ixj = i ^ j;
            if (ixj > i) {
                unsigned long long x = s[i], y = s[ixj];
                bool sw = ((i & k) == 0) ? (x > y) : (x < y);
                if (sw) { s[i] = y; s[ixj] = x; }
            }
        }
    }
    __syncthreads();
}

__device__ __forceinline__ void split8(const float4& a, const float4& b, float s,
                                       h8& hh, h8& ll) {
    float v0 = a.x * s, v1 = a.y * s, v2 = a.z * s, v3 = a.w * s;
    float v4 = b.x * s, v5 = b.y * s, v6 = b.z * s, v7 = b.w * s;
    hh[0] = (_Float16)v0; ll[0] = (_Float16)(v0 - (float)hh[0]);
    hh[1] = (_Float16)v1; ll[1] = (_Float16)(v1 - (float)hh[1]);
    hh[2] = (_Float16)v2; ll[2] = (_Float16)(v2 - (float)hh[2]);
    hh[3] = (_Float16)v3; ll[3] = (_Float16)(v3 - (float)hh[3]);
    hh[4] = (_Float16)v4; ll[4] = (_Float16)(v4 - (float)hh[4]);
    hh[5] = (_Float16)v5; ll[5] = (_Float16)(v5 - (float)hh[5]);
    hh[6] = (_Float16)v6; ll[6] = (_Float16)(v6 - (float)hh[6]);
    hh[7] = (_Float16)v7; ll[7] = (_Float16)(v7 - (float)hh[7]);
}

// XCD-chunked swizzle: col-fastest so same-row col-blocks share an XCD L2
__device__ __forceinline__ void swz_block(int nby, int& bm, int& bn) {
    unsigned id = blockIdx.x, g = gridDim.x, s = id;
    if ((g & 7u) == 0u) { unsigned c = g >> 3; s = (id & 7u) * c + (id >> 3); }
    bm = (int)(s / (unsigned)nby) * 128;
    bn = (int)(s % (unsigned)nby) * 128;
}

// LDS slot s (0..511) -> (row, kseg): row=(s>>6)*16+(s&15), ks=(s>>4)&3
__device__ __forceinline__ void slot_rc(int s, int& r, int& ks) {
    r  = ((s >> 6) << 4) + (s & 15);
    ks = (s >> 4) & 3;
}

// ---------------- dedup: flags -> exclusive scan -> compact ----------------
__global__ void k_clear(int* __restrict__ flags) {
    flags[blockIdx.x * 256 + threadIdx.x] = 0;
}
__global__ void k_mark(const int* __restrict__ ids, int* __restrict__ flags, int n) {
    int i = blockIdx.x * 256 + threadIdx.x;
    if (i < n) flags[ids[i]] = 1;
}
__global__ void k_scan_a(const int* __restrict__ flags, int* __restrict__ slots,
                         int* __restrict__ bsum) {
    int i = blockIdx.x * 256 + threadIdx.x;
    __shared__ int s[256];
    int v = flags[i];
    s[threadIdx.x] = v; __syncthreads();
    for (int o = 1; o < 256; o <<= 1) {
        int t2 = (threadIdx.x >= o) ? s[threadIdx.x - o] : 0;
        __syncthreads();
        s[threadIdx.x] += t2;
        __syncthreads();
    }
    slots[i] = s[threadIdx.x] - v;
    if (threadIdx.x == 255) bsum[blockIdx.x] = s[255];
}
__global__ void k_scan_b(int* __restrict__ bsum, int* __restrict__ mcount) {
    __shared__ int s[256];
    int v = bsum[threadIdx.x];
    s[threadIdx.x] = v; __syncthreads();
    for (int o = 1; o < 256; o <<= 1) {
        int t2 = (threadIdx.x >= o) ? s[threadIdx.x - o] : 0;
        __syncthreads();
        s[threadIdx.x] += t2;
        __syncthreads();
    }
    bsum[threadIdx.x] = s[threadIdx.x] - v;
    if (threadIdx.x == 255) *mcount = s[255];
}
__global__ void k_scan_c(const int* __restrict__ flags, int* __restrict__ slots,
                         const int* __restrict__ bsum, int* __restrict__ ulist) {
    int i = blockIdx.x * 256 + threadIdx.x;
    int slot = slots[i] + bsum[blockIdx.x];
    slots[i] = slot;
    if (flags[i]) ulist[slot] = i;
}

// ---------------- B split+transpose: planes [N][K] f16 hi/lo, scaled ----------------
__global__ void k_split_bT(const float* __restrict__ B, int ldb, int K,
                           _Float16* __restrict__ Ph, _Float16* __restrict__ Pl,
                           int row_off, int ldp, float scale)
{
    int n = blockIdx.x;
    for (int k = threadIdx.x; k < K; k += 256) {
        float v = B[(long long)k * ldb + n] * scale;
        _Float16 h = (_Float16)v;
        _Float16 l = (_Float16)(v - (float)h);
        Ph[(long long)(row_off + n) * ldp + k] = h;
        Pl[(long long)(row_off + n) * ldp + k] = l;
    }
}

// ---------------- split-f16 MFMA GEMM (f32-A, in-loop split), frag-packed LDS ----------------
// C = op((A [+A2]) @ B * inv_scale + bias); B pre-split planes [N][K].
// acc += mfma(ah,bh)+mfma(ah,bl)+mfma(al,bh)  (chain identical to rounds 7-11).
// BM=BN=128, BK=32, 256 thr (2x2 waves, 64x64/wave). Staging writes slot=chunk
// (consecutive lanes -> consecutive 16B slots, conflict-free); frag reads contiguous.
// Optional plane output Ch/Cl (scale out_scale).
__global__ __launch_bounds__(256) void gemm_mfma3(
    const float* __restrict__ A, int lda,
    const int* __restrict__ gather, const float* __restrict__ A2,
    const _Float16* __restrict__ Bh, const _Float16* __restrict__ Bl,
    float* __restrict__ C, int ldc,
    _Float16* __restrict__ Ch, _Float16* __restrict__ Cl, int ldch,
    int nby, int Mstatic, const int* __restrict__ mcount,
    int K, const float* __restrict__ bias, int relu,
    float ascale, float inv_scale, float out_scale)
{
    int mlim = Mstatic;
    if (mcount) mlim = *mcount;
    int bm, bn;
    swz_block(nby, bm, bn);
    if (bm >= mlim) return;

    __shared__ h8 AsH[512];
    __shared__ h8 AsL[512];
    __shared__ h8 BsH[512];
    __shared__ h8 BsL[512];

    const int t = threadIdx.x;
    const int lane = t & 63;
    const int wid  = t >> 6;
    const int aRt = (wid >> 1) * 4;
    const int bRt = (wid & 1) * 4;
    const int wr = (wid >> 1) * 64, wc = (wid & 1) * 64;

    // A staging: chunks c = t, t+256; slot = c
    const float* aptr[2];
    const float* aptr2[2];
    #pragma unroll
    for (int i = 0; i < 2; ++i) {
        int c = t + i * 256;
        int r, ks; slot_rc(c, r, ks);
        int grow = bm + r;
        long long g = 0;
        if (grow < mlim) g = gather ? (long long)gather[grow] : (long long)grow;
        aptr[i]  = A + g * lda + ks * 8;
        aptr2[i] = A2 ? (A2 + g * lda + ks * 8) : nullptr;
    }
    // B staging: chunks c = t + i*256 (i<4); plane = c>>9, slot = c&511
    const _Float16* bptr[4];
    int bpl[4];
    #pragma unroll
    for (int i = 0; i < 4; ++i) {
        int c = t + i * 256;
        bpl[i] = c >> 9;
        int s = c & 511;
        int r, ks; slot_rc(s, r, ks);
        bptr[i] = (bpl[i] ? Bl : Bh) + (long long)(bn + r) * K + ks * 8;
    }

    f32x4 acc[4][4];
    #pragma unroll
    for (int m = 0; m < 4; ++m)
        #pragma unroll
        for (int n = 0; n < 4; ++n)
            acc[m][n] = (f32x4){0.f, 0.f, 0.f, 0.f};

    float4 pa[2][2], pa2[2][2];
    h8 pb[4];
    #pragma unroll
    for (int i = 0; i < 2; ++i) {
        pa[i][0] = *(const float4*)(aptr[i]);
        pa[i][1] = *(const float4*)(aptr[i] + 4);
        if (A2) {
            pa2[i][0] = *(const float4*)(aptr2[i]);
            pa2[i][1] = *(const float4*)(aptr2[i] + 4);
        }
    }
    #pragma unroll
    for (int i = 0; i < 4; ++i) pb[i] = *(const h8*)(bptr[i]);

    const int nt = K / 32;
    for (int tI = 0; tI < nt; ++tI) {
        __syncthreads();
        #pragma unroll
        for (int i = 0; i < 2; ++i) {
            float4 x = pa[i][0], y = pa[i][1];
            if (A2) {
                x.x += pa2[i][0].x; x.y += pa2[i][0].y;
                x.z += pa2[i][0].z; x.w += pa2[i][0].w;
                y.x += pa2[i][1].x; y.y += pa2[i][1].y;
                y.z += pa2[i][1].z; y.w += pa2[i][1].w;
            }
            h8 hh, ll;
            split8(x, y, ascale, hh, ll);
            AsH[t + i * 256] = hh;
            AsL[t + i * 256] = ll;
        }
        #pragma unroll
        for (int i = 0; i < 4; ++i) {
            int s = (t + i * 256) & 511;
            (bpl[i] ? BsL : BsH)[s] = pb[i];
        }
        __syncthreads();
        if (tI + 1 < nt) {
            int k0 = (tI + 1) * 32;
            #pragma unroll
            for (int i = 0; i < 2; ++i) {
                pa[i][0] = *(const float4*)(aptr[i] + k0);
                pa[i][1] = *(const float4*)(aptr[i] + k0 + 4);
                if (A2) {
                    pa2[i][0] = *(const float4*)(aptr2[i] + k0);
                    pa2[i][1] = *(const float4*)(aptr2[i] + k0 + 4);
                }
            }
            #pragma unroll
            for (int i = 0; i < 4; ++i) pb[i] = *(const h8*)(bptr[i] + k0);
        }
        h8 ah_[4], al_[4];
        #pragma unroll
        for (int m = 0; m < 4; ++m) {
            ah_[m] = AsH[(aRt + m) * 64 + lane];
            al_[m] = AsL[(aRt + m) * 64 + lane];
        }
        #pragma unroll
        for (int n = 0; n < 4; ++n) {
            h8 bh_ = BsH[(bRt + n) * 64 + lane];
            h8 bl_ = BsL[(bRt + n) * 64 + lane];
            #pragma unroll
            for (int m = 0; m < 4; ++m) {
                acc[m][n] = __builtin_amdgcn_mfma_f32_16x16x32_f16(ah_[m], bh_, acc[m][n], 0, 0, 0);
                acc[m][n] = __builtin_amdgcn_mfma_f32_16x16x32_f16(ah_[m], bl_, acc[m][n], 0, 0, 0);
                acc[m][n] = __builtin_amdgcn_mfma_f32_16x16x32_f16(al_[m], bh_, acc[m][n], 0, 0, 0);
            }
        }
    }

    // epilogue: C/D layout col=lane&15, row=(lane>>4)*4+reg
    const int fr  = lane & 15;
    const int cr0 = (lane >> 4) * 4;
    #pragma unroll
    for (int m = 0; m < 4; ++m) {
        #pragma unroll
        for (int r = 0; r < 4; ++r) {
            int row = bm + wr + m * 16 + cr0 + r;
            if (row >= mlim) continue;
            #pragma unroll
            for (int n = 0; n < 4; ++n) {
                int col = bn + wc + n * 16 + fr;
                float v = acc[m][n][r] * inv_scale;
                if (bias) v += bias[col];
                if (relu) v = fmaxf(v, 0.f);
                if (Ch) {
                    float w = v * out_scale;
                    _Float16 hh = (_Float16)w;
                    Ch[(long long)row * ldch + col] = hh;
                    Cl[(long long)row * ldch + col] = (_Float16)(w - (float)hh);
                } else {
                    C[(long long)row * ldc + col] = v;
                }
            }
        }
    }
}

// ---------------- split-f16 MFMA GEMM (planes-A variant) ----------------
__global__ __launch_bounds__(256) void gemm_p3(
    const _Float16* __restrict__ Ah, const _Float16* __restrict__ Al,
    const _Float16* __restrict__ Bh, const _Float16* __restrict__ Bl,
    float* __restrict__ C, int ldc,
    int nby, int Mstatic, const int* __restrict__ mcount,
    int K, const float* __restrict__ bias, int relu, float inv_scale)
{
    int mlim = Mstatic;
    if (mcount) mlim = *mcount;
    int bm, bn;
    swz_block(nby, bm, bn);
    if (bm >= mlim) return;

    __shared__ h8 AsH[512];
    __shared__ h8 AsL[512];
    __shared__ h8 BsH[512];
    __shared__ h8 BsL[512];

    const int t = threadIdx.x;
    const int lane = t & 63;
    const int wid  = t >> 6;
    const int aRt = (wid >> 1) * 4;
    const int bRt = (wid & 1) * 4;
    const int wr = (wid >> 1) * 64, wc = (wid & 1) * 64;

    const _Float16* aptr[4];
    const _Float16* bptr[4];
    int apl[4], bpl[4];
    #pragma unroll
    for (int i = 0; i < 4; ++i) {
        int c = t + i * 256;
        apl[i] = c >> 9; bpl[i] = c >> 9;
        int s = c & 511;
        int r, ks; slot_rc(s, r, ks);
        int arow = bm + r; if (arow >= mlim) arow = bm;  // clamp (rows >= mlim unused)
        aptr[i] = (apl[i] ? Al : Ah) + (long long)arow * K + ks * 8;
        bptr[i] = (bpl[i] ? Bl : Bh) + (long long)(bn + r) * K + ks * 8;
    }

    f32x4 acc[4][4];
    #pragma unroll
    for (int m = 0; m < 4; ++m)
        #pragma unroll
        for (int n = 0; n < 4; ++n)
            acc[m][n] = (f32x4){0.f, 0.f, 0.f, 0.f};

    h8 pa[4], pb[4];
    #pragma unroll
    for (int i = 0; i < 4; ++i) {
        pa[i] = *(const h8*)(aptr[i]);
        pb[i] = *(const h8*)(bptr[i]);
    }

    const int nt = K / 32;
    for (int tI = 0; tI < nt; ++tI) {
        __syncthreads();
        #pragma unroll
        for (int i = 0; i < 4; ++i) {
            int s = (t + i * 256) & 511;
            (apl[i] ? AsL : AsH)[s] = pa[i];
            (bpl[i] ? BsL : BsH)[s] = pb[i];
        }
        __syncthreads();
        if (tI + 1 < nt) {
            int k0 = (tI + 1) * 32;
            #pragma unroll
            for (int i = 0; i < 4; ++i) {
                pa[i] = *(const h8*)(aptr[i] + k0);
                pb[i] = *(const h8*)(bptr[i] + k0);
            }
        }
        h8 ah_[4], al_[4];
        #pragma unroll
        for (int m = 0; m < 4; ++m) {
            ah_[m] = AsH[(aRt + m) * 64 + lane];
            al_[m] = AsL[(aRt + m) * 64 + lane];
        }
        #pragma unroll
        for (int n = 0; n < 4; ++n) {
            h8 bh_ = BsH[(bRt + n) * 64 + lane];
            h8 bl_ = BsL[(bRt + n) * 64 + lane];
            #pragma unroll
            for (int m = 0; m < 4; ++m) {
                acc[m][n] = __builtin_amdgcn_mfma_f32_16x16x32_f16(ah_[m], bh_, acc[m][n], 0, 0, 0);
                acc[m][n] = __builtin_amdgcn_mfma_f32_16x16x32_f16(ah_[m], bl_, acc[m][n], 0, 0, 0);
                acc[m][n] = __builtin_amdgcn_mfma_f32_16x16x32_f16(al_[m], bh_, acc[m][n], 0, 0, 0);
            }
        }
    }

    const int fr  = lane & 15;
    const int cr0 = (lane >> 4) * 4;
    #pragma unroll
    for (int m = 0; m < 4; ++m) {
        #pragma unroll
        for (int r = 0; r < 4; ++r) {
            int row = bm + wr + m * 16 + cr0 + r;
            if (row >= mlim) continue;
            float* crow = C + (long long)row * ldc;
            #pragma unroll
            for (int n = 0; n < 4; ++n) {
                int col = bn + wc + n * 16 + fr;
                float v = acc[m][n][r] * inv_scale;
                if (bias) v += bias[col];
                if (relu) v = fmaxf(v, 0.f);
                crow[col] = v;
            }
        }
    }
}

// ---------------- in-place LayerNorm over rows of 256 ----------------
__global__ __launch_bounds__(256) void ln256_inplace(
    float* __restrict__ Y, const float* __restrict__ g, const float* __restrict__ b,
    int Mstatic, const int* __restrict__ mcount)
{
    int row = blockIdx.x;
    int mlim = mcount ? *mcount : Mstatic;
    if (row >= mlim) return;
    int d = threadIdx.x;
    float v = Y[(long long)row * 256 + d];
    __shared__ float red[256];
    red[d] = v; __syncthreads();
    for (int off = 128; off; off >>= 1) { if (d < off) red[d] += red[d + off]; __syncthreads(); }
    float mu = red[0] * (1.f / 256.f);
    __syncthreads();
    float dv = v - mu;
    red[d] = dv * dv; __syncthreads();
    for (int off = 128; off; off >>= 1) { if (d < off) red[d] += red[d + off]; __syncthreads(); }
    float var = red[0] * (1.f / 256.f);
    float out = g[d] * dv * (1.f / sqrtf(var + 1e-5f)) + b[d];
    Y[(long long)row * 256 + d] = out;
}

// ---------------- phase-1 scores: score = tanh(tvp + A[slot[id]]) . am_w2 ----------------
__global__ __launch_bounds__(256) void p1score(
    const float* __restrict__ tvp, const float* __restrict__ AK,
    const int* __restrict__ slots, const float* __restrict__ am_w2,
    const int* __restrict__ ids, float* __restrict__ scores)
{
    int bl = blockIdx.x;            // 0..799 == (b*50+l)
    int lane = threadIdx.x & 63;
    int wv   = threadIdx.x >> 6;    // 0..3
    float4 tv = *(const float4*)(tvp + (long long)bl * 256 + lane * 4);
    float4 w2 = *(const float4*)(am_w2 + lane * 4);
    for (int s = wv * 16; s < wv * 16 + 16; ++s) {
        int slot = slots[ids[bl * 64 + s]];
        float4 a = *(const float4*)(AK + (long long)slot * 512 + lane * 4);
        double p = (double)tanhf(tv.x + a.x) * w2.x
                 + (double)tanhf(tv.y + a.y) * w2.y
                 + (double)tanhf(tv.z + a.z) * w2.z
                 + (double)tanhf(tv.w + a.w) * w2.w;
        #pragma unroll
        for (int off = 32; off; off >>= 1) p += __shfl_down(p, off);
        if (lane == 0) scores[bl * 64 + s] = (float)p;
    }
}

// ---------------- phase-1 full sort (top-64 of 64, stable desc) ----------------
__global__ __launch_bounds__(64) void p1sort(
    const float* __restrict__ scores, const int* __restrict__ ids_in,
    const int* __restrict__ mk_in, int* __restrict__ sel_ids, int* __restrict__ sel_mk)
{
    int bl = blockIdx.x;
    int i = threadIdx.x;
    __shared__ unsigned long long s[64];
    float sc = scores[bl * 64 + i];
    int mk = mk_in[bl * 64 + i];
    float key = mk ? sc : NEG_HUGE;
    s[i] = ((unsigned long long)(~f2sort(key)) << 32) | (unsigned)i;
    bitonic_u64(s, i, 64);
    int src = (int)(unsigned)(s[i] & 0xffffffffull);
    sel_ids[bl * 64 + i] = ids_in[bl * 64 + src];
    sel_mk [bl * 64 + i] = mk_in [bl * 64 + src];
}

// ---------------- E table: tiled gather-GEMM over K-half of AK ----------------
__global__ __launch_bounds__(256) void etab2(
    const float* __restrict__ qw, const float* __restrict__ AK,
    const int* __restrict__ slots, const int* __restrict__ sel_ids,
    float* __restrict__ E)
{
    const int l = blockIdx.x;   // 0..49
    const int b = blockIdx.y;   // 0..15
    __shared__ float Ks[16][64];
    __shared__ float Qs[16][68];
    __shared__ int rowA[64];
    const int t  = threadIdx.x;
    const int tx = t & 15, ty = t >> 4;
    if (t < 64) rowA[t] = slots[sel_ids[(b * kL + l) * 64 + t]];
    __syncthreads();

    const int rA = t >> 2;          // 0..63
    const int kA = (t & 3) * 4;
    const float* aptr = AK + (long long)rowA[rA] * 512 + 256 + kA;
    const float* qbase = qw + ((long long)b * kL + 1) * 256;
    const bool tsok = rA < 49;

    double acc[4][4];
    #pragma unroll
    for (int i = 0; i < 4; ++i)
        #pragma unroll
        for (int j = 0; j < 4; ++j) acc[i][j] = 0.0;

    for (int k0 = 0; k0 < 256; k0 += 16) {
        float4 av = *(const float4*)(aptr + k0);
        float4 bv = make_float4(0.f, 0.f, 0.f, 0.f);
        if (tsok) bv = *(const float4*)(qbase + (long long)rA * 256 + k0 + kA);
        __syncthreads();
        Ks[kA + 0][rA] = av.x; Ks[kA + 1][rA] = av.y;
        Ks[kA + 2][rA] = av.z; Ks[kA + 3][rA] = av.w;
        Qs[kA + 0][rA] = bv.x; Qs[kA + 1][rA] = bv.y;
        Qs[kA + 2][rA] = bv.z; Qs[kA + 3][rA] = bv.w;
        __syncthreads();
        #pragma unroll
        for (int k = 0; k < 16; ++k) {
            float a[4], q[4];
            *(float4*)&a[0] = *(const float4*)&Ks[k][tx * 4];
            *(float4*)&q[0] = *(const float4*)&Qs[k][ty * 4];
            #pragma unroll
            for (int i = 0; i < 4; ++i)
                #pragma unroll
                for (int j = 0; j < 4; ++j)
                    acc[i][j] += (double)a[i] * (double)q[j];
        }
    }
    #pragma unroll
    for (int j = 0; j < 4; ++j) {
        int ts = ty * 4 + j;
        if (ts >= 49) continue;
        #pragma unroll
        for (int i = 0; i < 4; ++i) {
            int s = tx * 4 + i;
            E[((long long)b * 49 + ts) * 3200 + l * 64 + s] = (float)acc[i][j];
        }
    }
}

// ---------------- sequential memory recurrence: 1 wave/batch, register bitonic ----------------
__global__ __launch_bounds__(64) void recur(
    const float* __restrict__ E, const int* __restrict__ sel_ids,
    const int* __restrict__ sel_mk, const int* __restrict__ lengths,
    int* __restrict__ memf, float* __restrict__ dout_mem)
{
    const int b = blockIdx.x;
    const int lane = threadIdx.x;

    int cid = sel_ids[(b * kL) * 64 + lane];
    int cmk = sel_mk [(b * kL) * 64 + lane];
    int ccd = lane;

    const int tlast = lengths[b] - 2;           // in [0,48]
    const float* Eb = E + (long long)b * 49 * 3200;

    for (int ts = 0; ts <= tlast; ++ts) {
        int nid = sel_ids[(b * kL + ts + 1) * 64 + lane];
        int nmk = sel_mk [(b * kL + ts + 1) * 64 + lane];
        const float* Et = Eb + (long long)ts * 3200;

        float k0 = cmk ? Et[ccd] : NEG_HUGE;
        float k1 = nmk ? Et[(ts + 1) * 64 + lane] : NEG_HUGE;
        unsigned long long s0 = ((unsigned long long)(~f2sort(k0)) << 32) | (unsigned)lane;
        unsigned long long s1 = ((unsigned long long)(~f2sort(k1)) << 32) | (unsigned)(64 + lane);

        #pragma unroll
        for (int k = 2; k <= 128; k <<= 1) {
            #pragma unroll
            for (int j = k >> 1; j > 0; j >>= 1) {
                if (j == 64) {
                    unsigned long long mn = s0 < s1 ? s0 : s1;
                    unsigned long long mx = s0 < s1 ? s1 : s0;
                    s0 = mn; s1 = mx;
                } else {
                    bool up   = (lane & j) == 0;
                    bool asc0 = (lane & k) == 0;
                    bool asc1 = (((lane + 64) & k) == 0);
                    unsigned long long p0 = __shfl_xor(s0, j, 64);
                    unsigned long long p1 = __shfl_xor(s1, j, 64);
                    bool km0 = (asc0 == up), km1 = (asc1 == up);
                    s0 = (km0 == (s0 < p0)) ? s0 : p0;
                    s1 = (km1 == (s1 < p1)) ? s1 : p1;
                }
            }
        }

        int src  = (int)(unsigned)(s0 & 0xffffffffull);
        int srcl = src & 63;
        int c_id = __shfl(cid, srcl, 64);
        int c_mk = __shfl(cmk, srcl, 64);
        int c_cd = __shfl(ccd, srcl, 64);
        int n_id = __shfl(nid, srcl, 64);
        int n_mk = __shfl(nmk, srcl, 64);
        bool isnew = src >= 64;
        cid = isnew ? n_id : c_id;
        cmk = isnew ? n_mk : c_mk;
        ccd = isnew ? ((ts + 1) * 64 + srcl) : c_cd;
    }

    memf[b * 64 + lane] = cid;
    dout_mem[b * 64 + lane] = (float)cid;
}

// ---------------- final pooling + output head (mem rows gathered from T) ----------------
__global__ __launch_bounds__(256) void head_k(
    const float* __restrict__ tva, const int* __restrict__ lengths,
    const float* __restrict__ T, const int* __restrict__ slots,
    const int* __restrict__ memf, const float* __restrict__ out_w,
    const float* __restrict__ out_b, float* __restrict__ dout)
{
    int b = blockIdx.x, d = threadIdx.x;
    int len = lengths[b];
    float vf = NEG_HUGE;
    for (int l = 0; l < len; ++l) vf = fmaxf(vf, tva[((long long)b * kL + l) * 256 + d]);
    float mv = NEG_HUGE;
    for (int m = 0; m < 64; ++m) {
        int slot = slots[memf[b * 64 + m]];
        mv = fmaxf(mv, T[(long long)slot * 256 + d]);
    }
    double p0 = (double)vf * out_w[d * 2 + 0] + (double)mv * out_w[(256 + d) * 2 + 0];
    double p1 = (double)vf * out_w[d * 2 + 1] + (double)mv * out_w[(256 + d) * 2 + 1];
    __shared__ double r0[256], r1[256];
    r0[d] = p0; r1[d] = p1; __syncthreads();
    for (int off = 128; off; off >>= 1) {
        if (d < off) { r0[d] += r0[d + off]; r1[d] += r1[d + off]; }
        __syncthreads();
    }
    if (d == 0) {
        dout[b * 2 + 0] = (float)(r0[0] + out_b[0]);
        dout[b * 2 + 1] = (float)(r1[0] + out_b[1]);
    }
}

// ---------------- host orchestration ----------------
extern "C" void kernel_launch(void* const* d_in, const int* in_sizes, int n_in,
                              void* d_out, int out_size, void* d_ws, size_t ws_size,
                              hipStream_t stream)
{
    const float* v_all  = (const float*)d_in[0];
    const float* tva    = (const float*)d_in[1];
    const float* emb    = (const float*)d_in[2];
    const float* bt_w1  = (const float*)d_in[3];
    const float* bt_b1  = (const float*)d_in[4];
    const float* bt_w2  = (const float*)d_in[5];
    const float* bt_b2  = (const float*)d_in[6];
    const float* bt_g   = (const float*)d_in[7];
    const float* bt_bb  = (const float*)d_in[8];
    const float* wq     = (const float*)d_in[9];
    const float* wk     = (const float*)d_in[10];
    const float* am_w1  = (const float*)d_in[11];
    const float* am_b1  = (const float*)d_in[12];
    const float* am_w2  = (const float*)d_in[13];
    const float* out_w  = (const float*)d_in[14];
    const float* out_b  = (const float*)d_in[15];
    const int*   in_txt = (const int*)d_in[16];
    const int*   mk_txt = (const int*)d_in[17];
    const int*   lens   = (const int*)d_in[18];
    float* dout = (float*)d_out;

    const float S12 = 4096.f, S7 = 128.f, S8 = 256.f;
    const float INV24 = 1.f / 16777216.f;   // 2^-24
    const float INV19 = 1.f / 524288.f;     // 2^-19
    const float INV20 = 1.f / 1048576.f;    // 2^-20

    size_t off = 0;
    float* W = (float*)d_ws;
    auto take = [&](size_t n) { float* p = W + off; off += (n + 3) & ~(size_t)3; return p; };
    auto takeh = [&](size_t nh) { return (_Float16*)take((nh + 1) / 2); };

    float* AKp  = take((size_t)kMaxUsed * 512);
    float* Tt   = take((size_t)kMaxUsed * 256);
    _Float16* Hph = takeh((size_t)kMaxUsed * 512);      // H planes (x S12)
    _Float16* Hpl = takeh((size_t)kMaxUsed * 512);
    float* Ep   = (float*)Hph;                          // alias: E used after Hph dead
    float* tvpP = take((size_t)800 * 256);
    float* qwP  = take((size_t)800 * 256);
    float* scP  = take((size_t)800 * 64);
    int*   selI = (int*)take((size_t)800 * 64);
    int*   selM = (int*)take((size_t)800 * 64);
    int*   flagsP = (int*)take(kNBLK);
    int*   slotsP = (int*)take(kNBLK);
    int*   ulist  = (int*)take(kNBLK);
    int*   bsum   = (int*)take(256);
    int*   mcount = (int*)take(16);
    int*   memfP  = (int*)take(1024);
    _Float16* W1h = takeh((size_t)512 * 768);
    _Float16* W1l = takeh((size_t)512 * 768);
    _Float16* W2h = takeh((size_t)256 * 512);
    _Float16* W2l = takeh((size_t)256 * 512);
    _Float16* BCh = takeh((size_t)512 * 256);
    _Float16* BCl = takeh((size_t)512 * 256);
    _Float16* ALh = takeh((size_t)256 * 256);
    _Float16* ALl = takeh((size_t)256 * 256);
    _Float16* WQh = takeh((size_t)256 * 256);
    _Float16* WQl = takeh((size_t)256 * 256);

    // 1) dedup pipeline + B-plane splits
    k_clear<<<dim3(256), dim3(256), 0, stream>>>(flagsP);
    k_mark <<<dim3(200), dim3(256), 0, stream>>>(in_txt, flagsP, 51200);
    k_scan_a<<<dim3(256), dim3(256), 0, stream>>>(flagsP, slotsP, bsum);
    k_scan_b<<<dim3(1),   dim3(256), 0, stream>>>(bsum, mcount);
    k_scan_c<<<dim3(256), dim3(256), 0, stream>>>(flagsP, slotsP, bsum, ulist);
    k_split_bT<<<dim3(512), dim3(256), 0, stream>>>(bt_w1, 512, 768, W1h, W1l, 0, 768, S12);
    k_split_bT<<<dim3(256), dim3(256), 0, stream>>>(bt_w2, 256, 512, W2h, W2l, 0, 512, S12);
    k_split_bT<<<dim3(256), dim3(256), 0, stream>>>(am_w1 + 256 * 256, 256, 256, BCh, BCl, 0,   256, S12);
    k_split_bT<<<dim3(256), dim3(256), 0, stream>>>(wk,                256, 256, BCh, BCl, 256, 256, S12);
    k_split_bT<<<dim3(256), dim3(256), 0, stream>>>(am_w1, 256, 256, ALh, ALl, 0, 256, S12);
    k_split_bT<<<dim3(256), dim3(256), 0, stream>>>(wq,    256, 256, WQh, WQl, 0, 256, S12);

    // 2) tvp = tva@am_w1_lo + am_b1 ; qw = (tva+v_all)@wq   (grid 14: no swizzle)
    gemm_mfma3<<<dim3(14), dim3(256), 0, stream>>>(
        tva, 256, nullptr, nullptr, ALh, ALl, tvpP, 256, nullptr, nullptr, 0,
        2, 800, nullptr, 256, am_b1, 0, S7, INV19, 1.f);
    gemm_mfma3<<<dim3(14), dim3(256), 0, stream>>>(
        tva, 256, nullptr, v_all, WQh, WQl, qwP, 256, nullptr, nullptr, 0,
        2, 800, nullptr, 256, nullptr, 0, S7, INV19, 1.f);

    // 3) tables: H = relu(emb[ulist]@W1+b1) -> planes; Y = H@W2+b2 -> Tt; LN; AK
    gemm_mfma3<<<dim3(1600), dim3(256), 0, stream>>>(
        emb, 768, ulist, nullptr, W1h, W1l, nullptr, 0, Hph, Hpl, 512,
        4, 0, mcount, 768, bt_b1, 1, S12, INV24, S12);
    gemm_p3<<<dim3(800), dim3(256), 0, stream>>>(
        Hph, Hpl, W2h, W2l, Tt, 256,
        2, 0, mcount, 512, bt_b2, 0, INV24);
    ln256_inplace<<<dim3(kMaxUsed), dim3(256), 0, stream>>>(Tt, bt_g, bt_bb, 0, mcount);
    gemm_mfma3<<<dim3(1600), dim3(256), 0, stream>>>(
        Tt, 256, nullptr, nullptr, BCh, BCl, AKp, 512, nullptr, nullptr, 0,
        4, 0, mcount, 256, nullptr, 0, S8, INV20, 1.f);

    // 4) phase-1 scores + stable full sort
    p1score<<<dim3(800), dim3(256), 0, stream>>>(tvpP, AKp, slotsP, am_w2, in_txt, scP);
    p1sort<<<dim3(800), dim3(64), 0, stream>>>(scP, in_txt, mk_txt, selI, selM);

    // 5) E table (overwrites Hph region — dead after Y GEMM)
    etab2<<<dim3(50, 16), dim3(256), 0, stream>>>(qwP, AKp, slotsP, selI, Ep);

    // 6) sequential recurrence -> memory_final (writes output 1)
    recur<<<dim3(16), dim3(64), 0, stream>>>(Ep, selI, selM, lens, memfP, dout + 32);

    // 7) pooling + output head (mem vectors gathered from T; writes output 0)
    head_k<<<dim3(16), dim3(256), 0, stream>>>(tva, lens, Tt, slotsP, memfP,
                                               out_w, out_b, dout);
}

// Round 13
// 702.926 us; speedup vs baseline: 1.0400x; 1.0400x over previous
//
#include <hip/hip_runtime.h>
#include <math.h>

// Problem constants
constexpr int kBS   = 16;
constexpr int kL    = 50;
constexpr int kNB   = 64;
constexpr int kD    = 256;
constexpr int kNBLK = 65536;
constexpr int kMaxUsed = 51200;          // 16*50*64 worst-case unique ids

#define NEG_HUGE (-3.402823466e38f)

typedef _Float16 h8 __attribute__((ext_vector_type(8)));
typedef float f32x4 __attribute__((ext_vector_type(4)));

// ---------------- helpers ----------------
__device__ __forceinline__ unsigned f2sort(float f) {
    unsigned u = __float_as_uint(f);
    return (u & 0x80000000u) ? ~u : (u | 0x80000000u);   // monotone ascending map
}

__device__ __forceinline__ void bitonic_u64(unsigned long long* s, int i, int n) {
    for (int k = 2; k <= n; k <<= 1) {
        for (int j = k >> 1; j > 0; j >>= 1) {
            __syncthreads();
            int ixj = i ^ j;
            if (ixj > i) {
                unsigned long long x = s[i], y = s[ixj];
                bool sw = ((i & k) == 0) ? (x > y) : (x < y);
                if (sw) { s[i] = y; s[ixj] = x; }
            }
        }
    }
    __syncthreads();
}

__device__ __forceinline__ void split8(const float4& a, const float4& b, float s,
                                       h8& hh, h8& ll) {
    float v0 = a.x * s, v1 = a.y * s, v2 = a.z * s, v3 = a.w * s;
    float v4 = b.x * s, v5 = b.y * s, v6 = b.z * s, v7 = b.w * s;
    hh[0] = (_Float16)v0; ll[0] = (_Float16)(v0 - (float)hh[0]);
    hh[1] = (_Float16)v1; ll[1] = (_Float16)(v1 - (float)hh[1]);
    hh[2] = (_Float16)v2; ll[2] = (_Float16)(v2 - (float)hh[2]);
    hh[3] = (_Float16)v3; ll[3] = (_Float16)(v3 - (float)hh[3]);
    hh[4] = (_Float16)v4; ll[4] = (_Float16)(v4 - (float)hh[4]);
    hh[5] = (_Float16)v5; ll[5] = (_Float16)(v5 - (float)hh[5]);
    hh[6] = (_Float16)v6; ll[6] = (_Float16)(v6 - (float)hh[6]);
    hh[7] = (_Float16)v7; ll[7] = (_Float16)(v7 - (float)hh[7]);
}

// XCD-chunked swizzle: col-fastest so same-row col-blocks share an XCD L2
__device__ __forceinline__ void swz_block(int nby, int& bm, int& bn) {
    unsigned id = blockIdx.x, g = gridDim.x, s = id;
    if ((g & 7u) == 0u) { unsigned c = g >> 3; s = (id & 7u) * c + (id >> 3); }
    bm = (int)(s / (unsigned)nby) * 128;
    bn = (int)(s % (unsigned)nby) * 128;
}

// LDS slot s (0..511) -> (row, kseg): row=(s>>6)*16+(s&15), ks=(s>>4)&3
__device__ __forceinline__ void slot_rc(int s, int& r, int& ks) {
    r  = ((s >> 6) << 4) + (s & 15);
    ks = (s >> 4) & 3;
}

// ---------------- dedup: flags -> exclusive scan -> compact ----------------
__global__ void k_clear(int* __restrict__ flags) {
    flags[blockIdx.x * 256 + threadIdx.x] = 0;
}
__global__ void k_mark(const int* __restrict__ ids, int* __restrict__ flags, int n) {
    int i = blockIdx.x * 256 + threadIdx.x;
    if (i < n) flags[ids[i]] = 1;
}
__global__ void k_scan_a(const int* __restrict__ flags, int* __restrict__ slots,
                         int* __restrict__ bsum) {
    int i = blockIdx.x * 256 + threadIdx.x;
    __shared__ int s[256];
    int v = flags[i];
    s[threadIdx.x] = v; __syncthreads();
    for (int o = 1; o < 256; o <<= 1) {
        int t2 = (threadIdx.x >= o) ? s[threadIdx.x - o] : 0;
        __syncthreads();
        s[threadIdx.x] += t2;
        __syncthreads();
    }
    slots[i] = s[threadIdx.x] - v;
    if (threadIdx.x == 255) bsum[blockIdx.x] = s[255];
}
__global__ void k_scan_b(int* __restrict__ bsum, int* __restrict__ mcount) {
    __shared__ int s[256];
    int v = bsum[threadIdx.x];
    s[threadIdx.x] = v; __syncthreads();
    for (int o = 1; o < 256; o <<= 1) {
        int t2 = (threadIdx.x >= o) ? s[threadIdx.x - o] : 0;
        __syncthreads();
        s[threadIdx.x] += t2;
        __syncthreads();
    }
    bsum[threadIdx.x] = s[threadIdx.x] - v;
    if (threadIdx.x == 255) *mcount = s[255];
}
__global__ void k_scan_c(const int* __restrict__ flags, int* __restrict__ slots,
                         const int* __restrict__ bsum, int* __restrict__ ulist) {
    int i = blockIdx.x * 256 + threadIdx.x;
    int slot = slots[i] + bsum[blockIdx.x];
    slots[i] = slot;
    if (flags[i]) ulist[slot] = i;
}

// ---------------- B split+transpose: planes [N][K] f16 hi/lo, scaled ----------------
__global__ void k_split_bT(const float* __restrict__ B, int ldb, int K,
                           _Float16* __restrict__ Ph, _Float16* __restrict__ Pl,
                           int row_off, int ldp, float scale)
{
    int n = blockIdx.x;
    for (int k = threadIdx.x; k < K; k += 256) {
        float v = B[(long long)k * ldb + n] * scale;
        _Float16 h = (_Float16)v;
        _Float16 l = (_Float16)(v - (float)h);
        Ph[(long long)(row_off + n) * ldp + k] = h;
        Pl[(long long)(row_off + n) * ldp + k] = l;
    }
}

// ---------------- split-f16 MFMA GEMM (f32-A in-loop split), frag-packed LDS ----------------
// C = op((A [+A2]) @ B * inv_scale + bias); B pre-split planes [N][K].
// acc += mfma(ah,bh)+mfma(ah,bl)+mfma(al,bh)  (chain identical to rounds 7-12).
// BM=BN=128, BK=32, 256 thr (2x2 waves, 64x64/wave). Staging slot = chunk index
// (consecutive lanes write consecutive 16B slots, conflict-free); frag reads contiguous.
__global__ __launch_bounds__(256) void gemm_mfma3(
    const float* __restrict__ A, int lda,
    const int* __restrict__ gather, const float* __restrict__ A2,
    const _Float16* __restrict__ Bh, const _Float16* __restrict__ Bl,
    float* __restrict__ C, int ldc,
    int nby, int Mstatic, const int* __restrict__ mcount,
    int K, const float* __restrict__ bias, int relu,
    float ascale, float inv_scale)
{
    int mlim = Mstatic;
    if (mcount) mlim = *mcount;
    int bm, bn;
    swz_block(nby, bm, bn);
    if (bm >= mlim) return;

    __shared__ h8 AsH[512];
    __shared__ h8 AsL[512];
    __shared__ h8 BsH[512];
    __shared__ h8 BsL[512];

    const int t = threadIdx.x;
    const int lane = t & 63;
    const int wid  = t >> 6;
    const int aRt = (wid >> 1) * 4;
    const int bRt = (wid & 1) * 4;
    const int wr = (wid >> 1) * 64, wc = (wid & 1) * 64;

    // A staging: chunks c = t, t+256; slot = c
    const float* aptr[2];
    const float* aptr2[2];
    #pragma unroll
    for (int i = 0; i < 2; ++i) {
        int c = t + i * 256;
        int r, ks; slot_rc(c, r, ks);
        int grow = bm + r;
        long long g = 0;
        if (grow < mlim) g = gather ? (long long)gather[grow] : (long long)grow;
        aptr[i]  = A + g * lda + ks * 8;
        aptr2[i] = A2 ? (A2 + g * lda + ks * 8) : nullptr;
    }
    // B staging: chunks c = t + i*256 (i<4); plane = c>>9, slot = c&511
    const _Float16* bptr[4];
    int bpl[4];
    #pragma unroll
    for (int i = 0; i < 4; ++i) {
        int c = t + i * 256;
        bpl[i] = c >> 9;
        int s = c & 511;
        int r, ks; slot_rc(s, r, ks);
        bptr[i] = (bpl[i] ? Bl : Bh) + (long long)(bn + r) * K + ks * 8;
    }

    f32x4 acc[4][4];
    #pragma unroll
    for (int m = 0; m < 4; ++m)
        #pragma unroll
        for (int n = 0; n < 4; ++n)
            acc[m][n] = (f32x4){0.f, 0.f, 0.f, 0.f};

    float4 pa[2][2], pa2[2][2];
    h8 pb[4];
    #pragma unroll
    for (int i = 0; i < 2; ++i) {
        pa[i][0] = *(const float4*)(aptr[i]);
        pa[i][1] = *(const float4*)(aptr[i] + 4);
        if (A2) {
            pa2[i][0] = *(const float4*)(aptr2[i]);
            pa2[i][1] = *(const float4*)(aptr2[i] + 4);
        }
    }
    #pragma unroll
    for (int i = 0; i < 4; ++i) pb[i] = *(const h8*)(bptr[i]);

    const int nt = K / 32;
    for (int tI = 0; tI < nt; ++tI) {
        __syncthreads();
        #pragma unroll
        for (int i = 0; i < 2; ++i) {
            float4 x = pa[i][0], y = pa[i][1];
            if (A2) {
                x.x += pa2[i][0].x; x.y += pa2[i][0].y;
                x.z += pa2[i][0].z; x.w += pa2[i][0].w;
                y.x += pa2[i][1].x; y.y += pa2[i][1].y;
                y.z += pa2[i][1].z; y.w += pa2[i][1].w;
            }
            h8 hh, ll;
            split8(x, y, ascale, hh, ll);
            AsH[t + i * 256] = hh;
            AsL[t + i * 256] = ll;
        }
        #pragma unroll
        for (int i = 0; i < 4; ++i) {
            int s = (t + i * 256) & 511;
            (bpl[i] ? BsL : BsH)[s] = pb[i];
        }
        __syncthreads();
        if (tI + 1 < nt) {
            int k0 = (tI + 1) * 32;
            #pragma unroll
            for (int i = 0; i < 2; ++i) {
                pa[i][0] = *(const float4*)(aptr[i] + k0);
                pa[i][1] = *(const float4*)(aptr[i] + k0 + 4);
                if (A2) {
                    pa2[i][0] = *(const float4*)(aptr2[i] + k0);
                    pa2[i][1] = *(const float4*)(aptr2[i] + k0 + 4);
                }
            }
            #pragma unroll
            for (int i = 0; i < 4; ++i) pb[i] = *(const h8*)(bptr[i] + k0);
        }
        h8 ah_[4], al_[4];
        #pragma unroll
        for (int m = 0; m < 4; ++m) {
            ah_[m] = AsH[(aRt + m) * 64 + lane];
            al_[m] = AsL[(aRt + m) * 64 + lane];
        }
        #pragma unroll
        for (int n = 0; n < 4; ++n) {
            h8 bh_ = BsH[(bRt + n) * 64 + lane];
            h8 bl_ = BsL[(bRt + n) * 64 + lane];
            #pragma unroll
            for (int m = 0; m < 4; ++m) {
                acc[m][n] = __builtin_amdgcn_mfma_f32_16x16x32_f16(ah_[m], bh_, acc[m][n], 0, 0, 0);
                acc[m][n] = __builtin_amdgcn_mfma_f32_16x16x32_f16(ah_[m], bl_, acc[m][n], 0, 0, 0);
                acc[m][n] = __builtin_amdgcn_mfma_f32_16x16x32_f16(al_[m], bh_, acc[m][n], 0, 0, 0);
            }
        }
    }

    // epilogue: C/D layout col=lane&15, row=(lane>>4)*4+reg
    const int fr  = lane & 15;
    const int cr0 = (lane >> 4) * 4;
    #pragma unroll
    for (int m = 0; m < 4; ++m) {
        #pragma unroll
        for (int r = 0; r < 4; ++r) {
            int row = bm + wr + m * 16 + cr0 + r;
            if (row >= mlim) continue;
            float* crow = C + (long long)row * ldc;
            #pragma unroll
            for (int n = 0; n < 4; ++n) {
                int col = bn + wc + n * 16 + fr;
                float v = acc[m][n][r] * inv_scale;
                if (bias) v += bias[col];
                if (relu) v = fmaxf(v, 0.f);
                crow[col] = v;
            }
        }
    }
}

// ---------------- in-place LayerNorm over rows of 256 ----------------
__global__ __launch_bounds__(256) void ln256_inplace(
    float* __restrict__ Y, const float* __restrict__ g, const float* __restrict__ b,
    int Mstatic, const int* __restrict__ mcount)
{
    int row = blockIdx.x;
    int mlim = mcount ? *mcount : Mstatic;
    if (row >= mlim) return;
    int d = threadIdx.x;
    float v = Y[(long long)row * 256 + d];
    __shared__ float red[256];
    red[d] = v; __syncthreads();
    for (int off = 128; off; off >>= 1) { if (d < off) red[d] += red[d + off]; __syncthreads(); }
    float mu = red[0] * (1.f / 256.f);
    __syncthreads();
    float dv = v - mu;
    red[d] = dv * dv; __syncthreads();
    for (int off = 128; off; off >>= 1) { if (d < off) red[d] += red[d + off]; __syncthreads(); }
    float var = red[0] * (1.f / 256.f);
    float out = g[d] * dv * (1.f / sqrtf(var + 1e-5f)) + b[d];
    Y[(long long)row * 256 + d] = out;
}

// ---------------- phase-1 scores: score = tanh(tvp + A[slot[id]]) . am_w2 ----------------
__global__ __launch_bounds__(256) void p1score(
    const float* __restrict__ tvp, const float* __restrict__ AK,
    const int* __restrict__ slots, const float* __restrict__ am_w2,
    const int* __restrict__ ids, float* __restrict__ scores)
{
    int bl = blockIdx.x;            // 0..799 == (b*50+l)
    int lane = threadIdx.x & 63;
    int wv   = threadIdx.x >> 6;    // 0..3
    float4 tv = *(const float4*)(tvp + (long long)bl * 256 + lane * 4);
    float4 w2 = *(const float4*)(am_w2 + lane * 4);
    for (int s = wv * 16; s < wv * 16 + 16; ++s) {
        int slot = slots[ids[bl * 64 + s]];
        float4 a = *(const float4*)(AK + (long long)slot * 512 + lane * 4);
        double p = (double)tanhf(tv.x + a.x) * w2.x
                 + (double)tanhf(tv.y + a.y) * w2.y
                 + (double)tanhf(tv.z + a.z) * w2.z
                 + (double)tanhf(tv.w + a.w) * w2.w;
        #pragma unroll
        for (int off = 32; off; off >>= 1) p += __shfl_down(p, off);
        if (lane == 0) scores[bl * 64 + s] = (float)p;
    }
}

// ---------------- phase-1 full sort (top-64 of 64, stable desc) ----------------
__global__ __launch_bounds__(64) void p1sort(
    const float* __restrict__ scores, const int* __restrict__ ids_in,
    const int* __restrict__ mk_in, int* __restrict__ sel_ids, int* __restrict__ sel_mk)
{
    int bl = blockIdx.x;
    int i = threadIdx.x;
    __shared__ unsigned long long s[64];
    float sc = scores[bl * 64 + i];
    int mk = mk_in[bl * 64 + i];
    float key = mk ? sc : NEG_HUGE;
    s[i] = ((unsigned long long)(~f2sort(key)) << 32) | (unsigned)i;
    bitonic_u64(s, i, 64);
    int src = (int)(unsigned)(s[i] & 0xffffffffull);
    sel_ids[bl * 64 + i] = ids_in[bl * 64 + src];
    sel_mk [bl * 64 + i] = mk_in [bl * 64 + src];
}

// ---------------- E table: tiled gather-GEMM over K-half of AK ----------------
__global__ __launch_bounds__(256) void etab2(
    const float* __restrict__ qw, const float* __restrict__ AK,
    const int* __restrict__ slots, const int* __restrict__ sel_ids,
    float* __restrict__ E)
{
    const int l = blockIdx.x;   // 0..49
    const int b = blockIdx.y;   // 0..15
    __shared__ float Ks[16][64];
    __shared__ float Qs[16][68];
    __shared__ int rowA[64];
    const int t  = threadIdx.x;
    const int tx = t & 15, ty = t >> 4;
    if (t < 64) rowA[t] = slots[sel_ids[(b * kL + l) * 64 + t]];
    __syncthreads();

    const int rA = t >> 2;          // 0..63
    const int kA = (t & 3) * 4;
    const float* aptr = AK + (long long)rowA[rA] * 512 + 256 + kA;
    const float* qbase = qw + ((long long)b * kL + 1) * 256;
    const bool tsok = rA < 49;

    double acc[4][4];
    #pragma unroll
    for (int i = 0; i < 4; ++i)
        #pragma unroll
        for (int j = 0; j < 4; ++j) acc[i][j] = 0.0;

    for (int k0 = 0; k0 < 256; k0 += 16) {
        float4 av = *(const float4*)(aptr + k0);
        float4 bv = make_float4(0.f, 0.f, 0.f, 0.f);
        if (tsok) bv = *(const float4*)(qbase + (long long)rA * 256 + k0 + kA);
        __syncthreads();
        Ks[kA + 0][rA] = av.x; Ks[kA + 1][rA] = av.y;
        Ks[kA + 2][rA] = av.z; Ks[kA + 3][rA] = av.w;
        Qs[kA + 0][rA] = bv.x; Qs[kA + 1][rA] = bv.y;
        Qs[kA + 2][rA] = bv.z; Qs[kA + 3][rA] = bv.w;
        __syncthreads();
        #pragma unroll
        for (int k = 0; k < 16; ++k) {
            float a[4], q[4];
            *(float4*)&a[0] = *(const float4*)&Ks[k][tx * 4];
            *(float4*)&q[0] = *(const float4*)&Qs[k][ty * 4];
            #pragma unroll
            for (int i = 0; i < 4; ++i)
                #pragma unroll
                for (int j = 0; j < 4; ++j)
                    acc[i][j] += (double)a[i] * (double)q[j];
        }
    }
    #pragma unroll
    for (int j = 0; j < 4; ++j) {
        int ts = ty * 4 + j;
        if (ts >= 49) continue;
        #pragma unroll
        for (int i = 0; i < 4; ++i) {
            int s = tx * 4 + i;
            E[((long long)b * 49 + ts) * 3200 + l * 64 + s] = (float)acc[i][j];
        }
    }
}

// ---------------- sequential memory recurrence: 1 wave/batch, register bitonic ----------------
__global__ __launch_bounds__(64) void recur(
    const float* __restrict__ E, const int* __restrict__ sel_ids,
    const int* __restrict__ sel_mk, const int* __restrict__ lengths,
    int* __restrict__ memf, float* __restrict__ dout_mem)
{
    const int b = blockIdx.x;
    const int lane = threadIdx.x;

    int cid = sel_ids[(b * kL) * 64 + lane];
    int cmk = sel_mk [(b * kL) * 64 + lane];
    int ccd = lane;

    const int tlast = lengths[b] - 2;           // in [0,48]
    const float* Eb = E + (long long)b * 49 * 3200;

    for (int ts = 0; ts <= tlast; ++ts) {
        int nid = sel_ids[(b * kL + ts + 1) * 64 + lane];
        int nmk = sel_mk [(b * kL + ts + 1) * 64 + lane];
        const float* Et = Eb + (long long)ts * 3200;

        float k0 = cmk ? Et[ccd] : NEG_HUGE;
        float k1 = nmk ? Et[(ts + 1) * 64 + lane] : NEG_HUGE;
        unsigned long long s0 = ((unsigned long long)(~f2sort(k0)) << 32) | (unsigned)lane;
        unsigned long long s1 = ((unsigned long long)(~f2sort(k1)) << 32) | (unsigned)(64 + lane);

        #pragma unroll
        for (int k = 2; k <= 128; k <<= 1) {
            #pragma unroll
            for (int j = k >> 1; j > 0; j >>= 1) {
                if (j == 64) {
                    unsigned long long mn = s0 < s1 ? s0 : s1;
                    unsigned long long mx = s0 < s1 ? s1 : s0;
                    s0 = mn; s1 = mx;
                } else {
                    bool up   = (lane & j) == 0;
                    bool asc0 = (lane & k) == 0;
                    bool asc1 = (((lane + 64) & k) == 0);
                    unsigned long long p0 = __shfl_xor(s0, j, 64);
                    unsigned long long p1 = __shfl_xor(s1, j, 64);
                    bool km0 = (asc0 == up), km1 = (asc1 == up);
                    s0 = (km0 == (s0 < p0)) ? s0 : p0;
                    s1 = (km1 == (s1 < p1)) ? s1 : p1;
                }
            }
        }

        int src  = (int)(unsigned)(s0 & 0xffffffffull);
        int srcl = src & 63;
        int c_id = __shfl(cid, srcl, 64);
        int c_mk = __shfl(cmk, srcl, 64);
        int c_cd = __shfl(ccd, srcl, 64);
        int n_id = __shfl(nid, srcl, 64);
        int n_mk = __shfl(nmk, srcl, 64);
        bool isnew = src >= 64;
        cid = isnew ? n_id : c_id;
        cmk = isnew ? n_mk : c_mk;
        ccd = isnew ? ((ts + 1) * 64 + srcl) : c_cd;
    }

    memf[b * 64 + lane] = cid;
    dout_mem[b * 64 + lane] = (float)cid;
}

// ---------------- final pooling + output head (mem rows gathered from T) ----------------
__global__ __launch_bounds__(256) void head_k(
    const float* __restrict__ tva, const int* __restrict__ lengths,
    const float* __restrict__ T, const int* __restrict__ slots,
    const int* __restrict__ memf, const float* __restrict__ out_w,
    const float* __restrict__ out_b, float* __restrict__ dout)
{
    int b = blockIdx.x, d = threadIdx.x;
    int len = lengths[b];
    float vf = NEG_HUGE;
    for (int l = 0; l < len; ++l) vf = fmaxf(vf, tva[((long long)b * kL + l) * 256 + d]);
    float mv = NEG_HUGE;
    for (int m = 0; m < 64; ++m) {
        int slot = slots[memf[b * 64 + m]];
        mv = fmaxf(mv, T[(long long)slot * 256 + d]);
    }
    double p0 = (double)vf * out_w[d * 2 + 0] + (double)mv * out_w[(256 + d) * 2 + 0];
    double p1 = (double)vf * out_w[d * 2 + 1] + (double)mv * out_w[(256 + d) * 2 + 1];
    __shared__ double r0[256], r1[256];
    r0[d] = p0; r1[d] = p1; __syncthreads();
    for (int off = 128; off; off >>= 1) {
        if (d < off) { r0[d] += r0[d + off]; r1[d] += r1[d + off]; }
        __syncthreads();
    }
    if (d == 0) {
        dout[b * 2 + 0] = (float)(r0[0] + out_b[0]);
        dout[b * 2 + 1] = (float)(r1[0] + out_b[1]);
    }
}

// ---------------- host orchestration ----------------
extern "C" void kernel_launch(void* const* d_in, const int* in_sizes, int n_in,
                              void* d_out, int out_size, void* d_ws, size_t ws_size,
                              hipStream_t stream)
{
    const float* v_all  = (const float*)d_in[0];
    const float* tva    = (const float*)d_in[1];
    const float* emb    = (const float*)d_in[2];
    const float* bt_w1  = (const float*)d_in[3];
    const float* bt_b1  = (const float*)d_in[4];
    const float* bt_w2  = (const float*)d_in[5];
    const float* bt_b2  = (const float*)d_in[6];
    const float* bt_g   = (const float*)d_in[7];
    const float* bt_bb  = (const float*)d_in[8];
    const float* wq     = (const float*)d_in[9];
    const float* wk     = (const float*)d_in[10];
    const float* am_w1  = (const float*)d_in[11];
    const float* am_b1  = (const float*)d_in[12];
    const float* am_w2  = (const float*)d_in[13];
    const float* out_w  = (const float*)d_in[14];
    const float* out_b  = (const float*)d_in[15];
    const int*   in_txt = (const int*)d_in[16];
    const int*   mk_txt = (const int*)d_in[17];
    const int*   lens   = (const int*)d_in[18];
    float* dout = (float*)d_out;

    const float S12 = 4096.f, S7 = 128.f, S8 = 256.f;
    const float INV24 = 1.f / 16777216.f;   // 2^-24
    const float INV19 = 1.f / 524288.f;     // 2^-19
    const float INV20 = 1.f / 1048576.f;    // 2^-20

    size_t off = 0;
    float* W = (float*)d_ws;
    auto take = [&](size_t n) { float* p = W + off; off += (n + 3) & ~(size_t)3; return p; };
    auto takeh = [&](size_t nh) { return (_Float16*)take((nh + 1) / 2); };

    float* AKp  = take((size_t)kMaxUsed * 512);
    float* Tt   = take((size_t)kMaxUsed * 256);
    float* Hp   = take((size_t)kMaxUsed * 512);
    float* Ep   = Hp;                                   // alias: E used after Hp is dead
    float* tvpP = take((size_t)800 * 256);
    float* qwP  = take((size_t)800 * 256);
    float* scP  = take((size_t)800 * 64);
    int*   selI = (int*)take((size_t)800 * 64);
    int*   selM = (int*)take((size_t)800 * 64);
    int*   flagsP = (int*)take(kNBLK);
    int*   slotsP = (int*)take(kNBLK);
    int*   ulist  = (int*)take(kNBLK);
    int*   bsum   = (int*)take(256);
    int*   mcount = (int*)take(16);
    int*   memfP  = (int*)take(1024);
    _Float16* W1h = takeh((size_t)512 * 768);
    _Float16* W1l = takeh((size_t)512 * 768);
    _Float16* W2h = takeh((size_t)256 * 512);
    _Float16* W2l = takeh((size_t)256 * 512);
    _Float16* BCh = takeh((size_t)512 * 256);
    _Float16* BCl = takeh((size_t)512 * 256);
    _Float16* ALh = takeh((size_t)256 * 256);
    _Float16* ALl = takeh((size_t)256 * 256);
    _Float16* WQh = takeh((size_t)256 * 256);
    _Float16* WQl = takeh((size_t)256 * 256);

    // 1) dedup pipeline + B-plane splits
    k_clear<<<dim3(256), dim3(256), 0, stream>>>(flagsP);
    k_mark <<<dim3(200), dim3(256), 0, stream>>>(in_txt, flagsP, 51200);
    k_scan_a<<<dim3(256), dim3(256), 0, stream>>>(flagsP, slotsP, bsum);
    k_scan_b<<<dim3(1),   dim3(256), 0, stream>>>(bsum, mcount);
    k_scan_c<<<dim3(256), dim3(256), 0, stream>>>(flagsP, slotsP, bsum, ulist);
    k_split_bT<<<dim3(512), dim3(256), 0, stream>>>(bt_w1, 512, 768, W1h, W1l, 0, 768, S12);
    k_split_bT<<<dim3(256), dim3(256), 0, stream>>>(bt_w2, 256, 512, W2h, W2l, 0, 512, S12);
    k_split_bT<<<dim3(256), dim3(256), 0, stream>>>(am_w1 + 256 * 256, 256, 256, BCh, BCl, 0,   256, S12);
    k_split_bT<<<dim3(256), dim3(256), 0, stream>>>(wk,                256, 256, BCh, BCl, 256, 256, S12);
    k_split_bT<<<dim3(256), dim3(256), 0, stream>>>(am_w1, 256, 256, ALh, ALl, 0, 256, S12);
    k_split_bT<<<dim3(256), dim3(256), 0, stream>>>(wq,    256, 256, WQh, WQl, 0, 256, S12);

    // 2) tvp = tva@am_w1_lo + am_b1 ; qw = (tva+v_all)@wq   (grid 14: no swizzle path)
    gemm_mfma3<<<dim3(14), dim3(256), 0, stream>>>(
        tva, 256, nullptr, nullptr, ALh, ALl, tvpP, 256,
        2, 800, nullptr, 256, am_b1, 0, S7, INV19);
    gemm_mfma3<<<dim3(14), dim3(256), 0, stream>>>(
        tva, 256, nullptr, v_all, WQh, WQl, qwP, 256,
        2, 800, nullptr, 256, nullptr, 0, S7, INV19);

    // 3) tables: H = relu(emb[ulist]@W1+b1) -> f32; Y = H@W2+b2 -> Tt; LN; AK
    gemm_mfma3<<<dim3(1600), dim3(256), 0, stream>>>(
        emb, 768, ulist, nullptr, W1h, W1l, Hp, 512,
        4, 0, mcount, 768, bt_b1, 1, S12, INV24);
    gemm_mfma3<<<dim3(800), dim3(256), 0, stream>>>(
        Hp, 512, nullptr, nullptr, W2h, W2l, Tt, 256,
        2, 0, mcount, 512, bt_b2, 0, S12, INV24);
    ln256_inplace<<<dim3(kMaxUsed), dim3(256), 0, stream>>>(Tt, bt_g, bt_bb, 0, mcount);
    gemm_mfma3<<<dim3(1600), dim3(256), 0, stream>>>(
        Tt, 256, nullptr, nullptr, BCh, BCl, AKp, 512,
        4, 0, mcount, 256, nullptr, 0, S8, INV20);

    // 4) phase-1 scores + stable full sort
    p1score<<<dim3(800), dim3(256), 0, stream>>>(tvpP, AKp, slotsP, am_w2, in_txt, scP);
    p1sort<<<dim3(800), dim3(64), 0, stream>>>(scP, in_txt, mk_txt, selI, selM);

    // 5) E table (overwrites Hp — Hp is dead after step 3's Y-GEMM)
    etab2<<<dim3(50, 16), dim3(256), 0, stream>>>(qwP, AKp, slotsP, selI, Ep);

    // 6) sequential recurrence -> memory_final (writes output 1)
    recur<<<dim3(16), dim3(64), 0, stream>>>(Ep, selI, selM, lens, memfP, dout + 32);

    // 7) pooling + output head (mem vectors gathered from T; writes output 0)
    head_k<<<dim3(16), dim3(256), 0, stream>>>(tva, lens, Tt, slotsP, memfP,
                                               out_w, out_b, dout);
}

// Round 14
// 613.295 us; speedup vs baseline: 1.1919x; 1.1461x over previous
//
#include <hip/hip_runtime.h>
#include <math.h>

// Problem constants
constexpr int kBS   = 16;
constexpr int kL    = 50;
constexpr int kNB   = 64;
constexpr int kD    = 256;
constexpr int kNBLK = 65536;
constexpr int kMaxUsed = 51200;          // 16*50*64 worst-case unique ids

#define NEG_HUGE (-3.402823466e38f)

typedef _Float16 h8 __attribute__((ext_vector_type(8)));
typedef float f32x4 __attribute__((ext_vector_type(4)));

// ---------------- helpers ----------------
__device__ __forceinline__ unsigned f2sort(float f) {
    unsigned u = __float_as_uint(f);
    return (u & 0x80000000u) ? ~u : (u | 0x80000000u);   // monotone ascending map
}

__device__ __forceinline__ void bitonic_u64(unsigned long long* s, int i, int n) {
    for (int k = 2; k <= n; k <<= 1) {
        for (int j = k >> 1; j > 0; j >>= 1) {
            __syncthreads();
            int ixj = i ^ j;
            if (ixj > i) {
                unsigned long long x = s[i], y = s[ixj];
                bool sw = ((i & k) == 0) ? (x > y) : (x < y);
                if (sw) { s[i] = y; s[ixj] = x; }
            }
        }
    }
    __syncthreads();
}

__device__ __forceinline__ void split8(const float4& a, const float4& b, float s,
                                       h8& hh, h8& ll) {
    float v0 = a.x * s, v1 = a.y * s, v2 = a.z * s, v3 = a.w * s;
    float v4 = b.x * s, v5 = b.y * s, v6 = b.z * s, v7 = b.w * s;
    hh[0] = (_Float16)v0; ll[0] = (_Float16)(v0 - (float)hh[0]);
    hh[1] = (_Float16)v1; ll[1] = (_Float16)(v1 - (float)hh[1]);
    hh[2] = (_Float16)v2; ll[2] = (_Float16)(v2 - (float)hh[2]);
    hh[3] = (_Float16)v3; ll[3] = (_Float16)(v3 - (float)hh[3]);
    hh[4] = (_Float16)v4; ll[4] = (_Float16)(v4 - (float)hh[4]);
    hh[5] = (_Float16)v5; ll[5] = (_Float16)(v5 - (float)hh[5]);
    hh[6] = (_Float16)v6; ll[6] = (_Float16)(v6 - (float)hh[6]);
    hh[7] = (_Float16)v7; ll[7] = (_Float16)(v7 - (float)hh[7]);
}

// Load-balanced XCD mapping: physical id -> XCD x = id&7 (round-robin dispatch).
// XCD x owns row-blocks {x, x+8, ...} (early-exit tail spreads evenly); the nby
// col-blocks of a row are consecutive on the same XCD (L2 reuse of A rows).
// Bijective iff gridDim.x % (8*nby) == 0; else plain col-fastest.
__device__ __forceinline__ void swz_block(int nby, int& bm, int& bn) {
    unsigned id = blockIdx.x, g = gridDim.x;
    unsigned rb, cb;
    if (g % (8u * (unsigned)nby) == 0u) {
        unsigned x = id & 7u, j = id >> 3;
        rb = x + 8u * (j / (unsigned)nby);
        cb = j % (unsigned)nby;
    } else {
        rb = id / (unsigned)nby;
        cb = id % (unsigned)nby;
    }
    bm = (int)rb * 128;
    bn = (int)cb * 128;
}

// LDS slot s (0..511) -> (row, kseg): row=(s>>6)*16+(s&15), ks=(s>>4)&3
__device__ __forceinline__ void slot_rc(int s, int& r, int& ks) {
    r  = ((s >> 6) << 4) + (s & 15);
    ks = (s >> 4) & 3;
}

// ---------------- dedup: flags -> exclusive scan -> compact ----------------
__global__ void k_clear(int* __restrict__ flags) {
    flags[blockIdx.x * 256 + threadIdx.x] = 0;
}
__global__ void k_mark(const int* __restrict__ ids, int* __restrict__ flags, int n) {
    int i = blockIdx.x * 256 + threadIdx.x;
    if (i < n) flags[ids[i]] = 1;
}
__global__ void k_scan_a(const int* __restrict__ flags, int* __restrict__ slots,
                         int* __restrict__ bsum) {
    int i = blockIdx.x * 256 + threadIdx.x;
    __shared__ int s[256];
    int v = flags[i];
    s[threadIdx.x] = v; __syncthreads();
    for (int o = 1; o < 256; o <<= 1) {
        int t2 = (threadIdx.x >= o) ? s[threadIdx.x - o] : 0;
        __syncthreads();
        s[threadIdx.x] += t2;
        __syncthreads();
    }
    slots[i] = s[threadIdx.x] - v;
    if (threadIdx.x == 255) bsum[blockIdx.x] = s[255];
}
__global__ void k_scan_b(int* __restrict__ bsum, int* __restrict__ mcount) {
    __shared__ int s[256];
    int v = bsum[threadIdx.x];
    s[threadIdx.x] = v; __syncthreads();
    for (int o = 1; o < 256; o <<= 1) {
        int t2 = (threadIdx.x >= o) ? s[threadIdx.x - o] : 0;
        __syncthreads();
        s[threadIdx.x] += t2;
        __syncthreads();
    }
    bsum[threadIdx.x] = s[threadIdx.x] - v;
    if (threadIdx.x == 255) *mcount = s[255];
}
__global__ void k_scan_c(const int* __restrict__ flags, int* __restrict__ slots,
                         const int* __restrict__ bsum, int* __restrict__ ulist) {
    int i = blockIdx.x * 256 + threadIdx.x;
    int slot = slots[i] + bsum[blockIdx.x];
    slots[i] = slot;
    if (flags[i]) ulist[slot] = i;
}

// ---------------- B split+transpose: planes [N][K] f16 hi/lo, scaled ----------------
__global__ void k_split_bT(const float* __restrict__ B, int ldb, int K,
                           _Float16* __restrict__ Ph, _Float16* __restrict__ Pl,
                           int row_off, int ldp, float scale)
{
    int n = blockIdx.x;
    for (int k = threadIdx.x; k < K; k += 256) {
        float v = B[(long long)k * ldb + n] * scale;
        _Float16 h = (_Float16)v;
        _Float16 l = (_Float16)(v - (float)h);
        Ph[(long long)(row_off + n) * ldp + k] = h;
        Pl[(long long)(row_off + n) * ldp + k] = l;
    }
}

// ---------------- split-f16 MFMA GEMM (f32-A in-loop split), frag-packed LDS ----------------
// C = op((A [+A2]) @ B * inv_scale + bias); B pre-split planes [N][K].
// acc += mfma(ah,bh)+mfma(ah,bl)+mfma(al,bh)  (chain identical to rounds 7-13).
// BM=BN=128, BK=32, 256 thr (2x2 waves, 64x64/wave). Staging slot = chunk index
// (consecutive lanes write consecutive 16B slots, conflict-free); frag reads contiguous.
__global__ __launch_bounds__(256) void gemm_mfma3(
    const float* __restrict__ A, int lda,
    const int* __restrict__ gather, const float* __restrict__ A2,
    const _Float16* __restrict__ Bh, const _Float16* __restrict__ Bl,
    float* __restrict__ C, int ldc,
    int nby, int Mstatic, const int* __restrict__ mcount,
    int K, const float* __restrict__ bias, int relu,
    float ascale, float inv_scale)
{
    int mlim = Mstatic;
    if (mcount) mlim = *mcount;
    int bm, bn;
    swz_block(nby, bm, bn);
    if (bm >= mlim) return;

    __shared__ h8 AsH[512];
    __shared__ h8 AsL[512];
    __shared__ h8 BsH[512];
    __shared__ h8 BsL[512];

    const int t = threadIdx.x;
    const int lane = t & 63;
    const int wid  = t >> 6;
    const int aRt = (wid >> 1) * 4;
    const int bRt = (wid & 1) * 4;
    const int wr = (wid >> 1) * 64, wc = (wid & 1) * 64;

    // A staging: chunks c = t, t+256; slot = c
    const float* aptr[2];
    const float* aptr2[2];
    #pragma unroll
    for (int i = 0; i < 2; ++i) {
        int c = t + i * 256;
        int r, ks; slot_rc(c, r, ks);
        int grow = bm + r;
        long long g = 0;
        if (grow < mlim) g = gather ? (long long)gather[grow] : (long long)grow;
        aptr[i]  = A + g * lda + ks * 8;
        aptr2[i] = A2 ? (A2 + g * lda + ks * 8) : nullptr;
    }
    // B staging: chunks c = t + i*256 (i<4); plane = c>>9, slot = c&511
    const _Float16* bptr[4];
    int bpl[4];
    #pragma unroll
    for (int i = 0; i < 4; ++i) {
        int c = t + i * 256;
        bpl[i] = c >> 9;
        int s = c & 511;
        int r, ks; slot_rc(s, r, ks);
        bptr[i] = (bpl[i] ? Bl : Bh) + (long long)(bn + r) * K + ks * 8;
    }

    f32x4 acc[4][4];
    #pragma unroll
    for (int m = 0; m < 4; ++m)
        #pragma unroll
        for (int n = 0; n < 4; ++n)
            acc[m][n] = (f32x4){0.f, 0.f, 0.f, 0.f};

    float4 pa[2][2], pa2[2][2];
    h8 pb[4];
    #pragma unroll
    for (int i = 0; i < 2; ++i) {
        pa[i][0] = *(const float4*)(aptr[i]);
        pa[i][1] = *(const float4*)(aptr[i] + 4);
        if (A2) {
            pa2[i][0] = *(const float4*)(aptr2[i]);
            pa2[i][1] = *(const float4*)(aptr2[i] + 4);
        }
    }
    #pragma unroll
    for (int i = 0; i < 4; ++i) pb[i] = *(const h8*)(bptr[i]);

    const int nt = K / 32;
    for (int tI = 0; tI < nt; ++tI) {
        __syncthreads();
        #pragma unroll
        for (int i = 0; i < 2; ++i) {
            float4 x = pa[i][0], y = pa[i][1];
            if (A2) {
                x.x += pa2[i][0].x; x.y += pa2[i][0].y;
                x.z += pa2[i][0].z; x.w += pa2[i][0].w;
                y.x += pa2[i][1].x; y.y += pa2[i][1].y;
                y.z += pa2[i][1].z; y.w += pa2[i][1].w;
            }
            h8 hh, ll;
            split8(x, y, ascale, hh, ll);
            AsH[t + i * 256] = hh;
            AsL[t + i * 256] = ll;
        }
        #pragma unroll
        for (int i = 0; i < 4; ++i) {
            int s = (t + i * 256) & 511;
            (bpl[i] ? BsL : BsH)[s] = pb[i];
        }
        __syncthreads();
        if (tI + 1 < nt) {
            int k0 = (tI + 1) * 32;
            #pragma unroll
            for (int i = 0; i < 2; ++i) {
                pa[i][0] = *(const float4*)(aptr[i] + k0);
                pa[i][1] = *(const float4*)(aptr[i] + k0 + 4);
                if (A2) {
                    pa2[i][0] = *(const float4*)(aptr2[i] + k0);
                    pa2[i][1] = *(const float4*)(aptr2[i] + k0 + 4);
                }
            }
            #pragma unroll
            for (int i = 0; i < 4; ++i) pb[i] = *(const h8*)(bptr[i] + k0);
        }
        h8 ah_[4], al_[4];
        #pragma unroll
        for (int m = 0; m < 4; ++m) {
            ah_[m] = AsH[(aRt + m) * 64 + lane];
            al_[m] = AsL[(aRt + m) * 64 + lane];
        }
        #pragma unroll
        for (int n = 0; n < 4; ++n) {
            h8 bh_ = BsH[(bRt + n) * 64 + lane];
            h8 bl_ = BsL[(bRt + n) * 64 + lane];
            #pragma unroll
            for (int m = 0; m < 4; ++m) {
                acc[m][n] = __builtin_amdgcn_mfma_f32_16x16x32_f16(ah_[m], bh_, acc[m][n], 0, 0, 0);
                acc[m][n] = __builtin_amdgcn_mfma_f32_16x16x32_f16(ah_[m], bl_, acc[m][n], 0, 0, 0);
                acc[m][n] = __builtin_amdgcn_mfma_f32_16x16x32_f16(al_[m], bh_, acc[m][n], 0, 0, 0);
            }
        }
    }

    // epilogue: C/D layout col=lane&15, row=(lane>>4)*4+reg
    const int fr  = lane & 15;
    const int cr0 = (lane >> 4) * 4;
    #pragma unroll
    for (int m = 0; m < 4; ++m) {
        #pragma unroll
        for (int r = 0; r < 4; ++r) {
            int row = bm + wr + m * 16 + cr0 + r;
            if (row >= mlim) continue;
            float* crow = C + (long long)row * ldc;
            #pragma unroll
            for (int n = 0; n < 4; ++n) {
                int col = bn + wc + n * 16 + fr;
                float v = acc[m][n][r] * inv_scale;
                if (bias) v += bias[col];
                if (relu) v = fmaxf(v, 0.f);
                crow[col] = v;
            }
        }
    }
}

// ---------------- in-place LayerNorm over rows of 256 ----------------
__global__ __launch_bounds__(256) void ln256_inplace(
    float* __restrict__ Y, const float* __restrict__ g, const float* __restrict__ b,
    int Mstatic, const int* __restrict__ mcount)
{
    int row = blockIdx.x;
    int mlim = mcount ? *mcount : Mstatic;
    if (row >= mlim) return;
    int d = threadIdx.x;
    float v = Y[(long long)row * 256 + d];
    __shared__ float red[256];
    red[d] = v; __syncthreads();
    for (int off = 128; off; off >>= 1) { if (d < off) red[d] += red[d + off]; __syncthreads(); }
    float mu = red[0] * (1.f / 256.f);
    __syncthreads();
    float dv = v - mu;
    red[d] = dv * dv; __syncthreads();
    for (int off = 128; off; off >>= 1) { if (d < off) red[d] += red[d + off]; __syncthreads(); }
    float var = red[0] * (1.f / 256.f);
    float out = g[d] * dv * (1.f / sqrtf(var + 1e-5f)) + b[d];
    Y[(long long)row * 256 + d] = out;
}

// ---------------- phase-1 scores: score = tanh(tvp + A[slot[id]]) . am_w2 ----------------
__global__ __launch_bounds__(256) void p1score(
    const float* __restrict__ tvp, const float* __restrict__ AK,
    const int* __restrict__ slots, const float* __restrict__ am_w2,
    const int* __restrict__ ids, float* __restrict__ scores)
{
    int bl = blockIdx.x;            // 0..799 == (b*50+l)
    int lane = threadIdx.x & 63;
    int wv   = threadIdx.x >> 6;    // 0..3
    float4 tv = *(const float4*)(tvp + (long long)bl * 256 + lane * 4);
    float4 w2 = *(const float4*)(am_w2 + lane * 4);
    for (int s = wv * 16; s < wv * 16 + 16; ++s) {
        int slot = slots[ids[bl * 64 + s]];
        float4 a = *(const float4*)(AK + (long long)slot * 512 + lane * 4);
        double p = (double)tanhf(tv.x + a.x) * w2.x
                 + (double)tanhf(tv.y + a.y) * w2.y
                 + (double)tanhf(tv.z + a.z) * w2.z
                 + (double)tanhf(tv.w + a.w) * w2.w;
        #pragma unroll
        for (int off = 32; off; off >>= 1) p += __shfl_down(p, off);
        if (lane == 0) scores[bl * 64 + s] = (float)p;
    }
}

// ---------------- phase-1 full sort (top-64 of 64, stable desc) ----------------
__global__ __launch_bounds__(64) void p1sort(
    const float* __restrict__ scores, const int* __restrict__ ids_in,
    const int* __restrict__ mk_in, int* __restrict__ sel_ids, int* __restrict__ sel_mk)
{
    int bl = blockIdx.x;
    int i = threadIdx.x;
    __shared__ unsigned long long s[64];
    float sc = scores[bl * 64 + i];
    int mk = mk_in[bl * 64 + i];
    float key = mk ? sc : NEG_HUGE;
    s[i] = ((unsigned long long)(~f2sort(key)) << 32) | (unsigned)i;
    bitonic_u64(s, i, 64);
    int src = (int)(unsigned)(s[i] & 0xffffffffull);
    sel_ids[bl * 64 + i] = ids_in[bl * 64 + src];
    sel_mk [bl * 64 + i] = mk_in [bl * 64 + src];
}

// ---------------- E table: tiled gather-GEMM over K-half of AK ----------------
__global__ __launch_bounds__(256) void etab2(
    const float* __restrict__ qw, const float* __restrict__ AK,
    const int* __restrict__ slots, const int* __restrict__ sel_ids,
    float* __restrict__ E)
{
    const int l = blockIdx.x;   // 0..49
    const int b = blockIdx.y;   // 0..15
    __shared__ float Ks[16][64];
    __shared__ float Qs[16][68];
    __shared__ int rowA[64];
    const int t  = threadIdx.x;
    const int tx = t & 15, ty = t >> 4;
    if (t < 64) rowA[t] = slots[sel_ids[(b * kL + l) * 64 + t]];
    __syncthreads();

    const int rA = t >> 2;          // 0..63
    const int kA = (t & 3) * 4;
    const float* aptr = AK + (long long)rowA[rA] * 512 + 256 + kA;
    const float* qbase = qw + ((long long)b * kL + 1) * 256;
    const bool tsok = rA < 49;

    double acc[4][4];
    #pragma unroll
    for (int i = 0; i < 4; ++i)
        #pragma unroll
        for (int j = 0; j < 4; ++j) acc[i][j] = 0.0;

    for (int k0 = 0; k0 < 256; k0 += 16) {
        float4 av = *(const float4*)(aptr + k0);
        float4 bv = make_float4(0.f, 0.f, 0.f, 0.f);
        if (tsok) bv = *(const float4*)(qbase + (long long)rA * 256 + k0 + kA);
        __syncthreads();
        Ks[kA + 0][rA] = av.x; Ks[kA + 1][rA] = av.y;
        Ks[kA + 2][rA] = av.z; Ks[kA + 3][rA] = av.w;
        Qs[kA + 0][rA] = bv.x; Qs[kA + 1][rA] = bv.y;
        Qs[kA + 2][rA] = bv.z; Qs[kA + 3][rA] = bv.w;
        __syncthreads();
        #pragma unroll
        for (int k = 0; k < 16; ++k) {
            float a[4], q[4];
            *(float4*)&a[0] = *(const float4*)&Ks[k][tx * 4];
            *(float4*)&q[0] = *(const float4*)&Qs[k][ty * 4];
            #pragma unroll
            for (int i = 0; i < 4; ++i)
                #pragma unroll
                for (int j = 0; j < 4; ++j)
                    acc[i][j] += (double)a[i] * (double)q[j];
        }
    }
    #pragma unroll
    for (int j = 0; j < 4; ++j) {
        int ts = ty * 4 + j;
        if (ts >= 49) continue;
        #pragma unroll
        for (int i = 0; i < 4; ++i) {
            int s = tx * 4 + i;
            E[((long long)b * 49 + ts) * 3200 + l * 64 + s] = (float)acc[i][j];
        }
    }
}

// ---------------- sequential memory recurrence: 1 wave/batch, register bitonic ----------------
__global__ __launch_bounds__(64) void recur(
    const float* __restrict__ E, const int* __restrict__ sel_ids,
    const int* __restrict__ sel_mk, const int* __restrict__ lengths,
    int* __restrict__ memf, float* __restrict__ dout_mem)
{
    const int b = blockIdx.x;
    const int lane = threadIdx.x;

    int cid = sel_ids[(b * kL) * 64 + lane];
    int cmk = sel_mk [(b * kL) * 64 + lane];
    int ccd = lane;

    const int tlast = lengths[b] - 2;           // in [0,48]
    const float* Eb = E + (long long)b * 49 * 3200;

    for (int ts = 0; ts <= tlast; ++ts) {
        int nid = sel_ids[(b * kL + ts + 1) * 64 + lane];
        int nmk = sel_mk [(b * kL + ts + 1) * 64 + lane];
        const float* Et = Eb + (long long)ts * 3200;

        float k0 = cmk ? Et[ccd] : NEG_HUGE;
        float k1 = nmk ? Et[(ts + 1) * 64 + lane] : NEG_HUGE;
        unsigned long long s0 = ((unsigned long long)(~f2sort(k0)) << 32) | (unsigned)lane;
        unsigned long long s1 = ((unsigned long long)(~f2sort(k1)) << 32) | (unsigned)(64 + lane);

        #pragma unroll
        for (int k = 2; k <= 128; k <<= 1) {
            #pragma unroll
            for (int j = k >> 1; j > 0; j >>= 1) {
                if (j == 64) {
                    unsigned long long mn = s0 < s1 ? s0 : s1;
                    unsigned long long mx = s0 < s1 ? s1 : s0;
                    s0 = mn; s1 = mx;
                } else {
                    bool up   = (lane & j) == 0;
                    bool asc0 = (lane & k) == 0;
                    bool asc1 = (((lane + 64) & k) == 0);
                    unsigned long long p0 = __shfl_xor(s0, j, 64);
                    unsigned long long p1 = __shfl_xor(s1, j, 64);
                    bool km0 = (asc0 == up), km1 = (asc1 == up);
                    s0 = (km0 == (s0 < p0)) ? s0 : p0;
                    s1 = (km1 == (s1 < p1)) ? s1 : p1;
                }
            }
        }

        int src  = (int)(unsigned)(s0 & 0xffffffffull);
        int srcl = src & 63;
        int c_id = __shfl(cid, srcl, 64);
        int c_mk = __shfl(cmk, srcl, 64);
        int c_cd = __shfl(ccd, srcl, 64);
        int n_id = __shfl(nid, srcl, 64);
        int n_mk = __shfl(nmk, srcl, 64);
        bool isnew = src >= 64;
        cid = isnew ? n_id : c_id;
        cmk = isnew ? n_mk : c_mk;
        ccd = isnew ? ((ts + 1) * 64 + srcl) : c_cd;
    }

    memf[b * 64 + lane] = cid;
    dout_mem[b * 64 + lane] = (float)cid;
}

// ---------------- final pooling + output head (mem rows gathered from T) ----------------
__global__ __launch_bounds__(256) void head_k(
    const float* __restrict__ tva, const int* __restrict__ lengths,
    const float* __restrict__ T, const int* __restrict__ slots,
    const int* __restrict__ memf, const float* __restrict__ out_w,
    const float* __restrict__ out_b, float* __restrict__ dout)
{
    int b = blockIdx.x, d = threadIdx.x;
    int len = lengths[b];
    float vf = NEG_HUGE;
    for (int l = 0; l < len; ++l) vf = fmaxf(vf, tva[((long long)b * kL + l) * 256 + d]);
    float mv = NEG_HUGE;
    for (int m = 0; m < 64; ++m) {
        int slot = slots[memf[b * 64 + m]];
        mv = fmaxf(mv, T[(long long)slot * 256 + d]);
    }
    double p0 = (double)vf * out_w[d * 2 + 0] + (double)mv * out_w[(256 + d) * 2 + 0];
    double p1 = (double)vf * out_w[d * 2 + 1] + (double)mv * out_w[(256 + d) * 2 + 1];
    __shared__ double r0[256], r1[256];
    r0[d] = p0; r1[d] = p1; __syncthreads();
    for (int off = 128; off; off >>= 1) {
        if (d < off) { r0[d] += r0[d + off]; r1[d] += r1[d + off]; }
        __syncthreads();
    }
    if (d == 0) {
        dout[b * 2 + 0] = (float)(r0[0] + out_b[0]);
        dout[b * 2 + 1] = (float)(r1[0] + out_b[1]);
    }
}

// ---------------- host orchestration ----------------
extern "C" void kernel_launch(void* const* d_in, const int* in_sizes, int n_in,
                              void* d_out, int out_size, void* d_ws, size_t ws_size,
                              hipStream_t stream)
{
    const float* v_all  = (const float*)d_in[0];
    const float* tva    = (const float*)d_in[1];
    const float* emb    = (const float*)d_in[2];
    const float* bt_w1  = (const float*)d_in[3];
    const float* bt_b1  = (const float*)d_in[4];
    const float* bt_w2  = (const float*)d_in[5];
    const float* bt_b2  = (const float*)d_in[6];
    const float* bt_g   = (const float*)d_in[7];
    const float* bt_bb  = (const float*)d_in[8];
    const float* wq     = (const float*)d_in[9];
    const float* wk     = (const float*)d_in[10];
    const float* am_w1  = (const float*)d_in[11];
    const float* am_b1  = (const float*)d_in[12];
    const float* am_w2  = (const float*)d_in[13];
    const float* out_w  = (const float*)d_in[14];
    const float* out_b  = (const float*)d_in[15];
    const int*   in_txt = (const int*)d_in[16];
    const int*   mk_txt = (const int*)d_in[17];
    const int*   lens   = (const int*)d_in[18];
    float* dout = (float*)d_out;

    const float S12 = 4096.f, S7 = 128.f, S8 = 256.f;
    const float INV24 = 1.f / 16777216.f;   // 2^-24
    const float INV19 = 1.f / 524288.f;     // 2^-19
    const float INV20 = 1.f / 1048576.f;    // 2^-20

    size_t off = 0;
    float* W = (float*)d_ws;
    auto take = [&](size_t n) { float* p = W + off; off += (n + 3) & ~(size_t)3; return p; };
    auto takeh = [&](size_t nh) { return (_Float16*)take((nh + 1) / 2); };

    float* AKp  = take((size_t)kMaxUsed * 512);
    float* Tt   = take((size_t)kMaxUsed * 256);
    float* Hp   = take((size_t)kMaxUsed * 512);
    float* Ep   = Hp;                                   // alias: E used after Hp is dead
    float* tvpP = take((size_t)800 * 256);
    float* qwP  = take((size_t)800 * 256);
    float* scP  = take((size_t)800 * 64);
    int*   selI = (int*)take((size_t)800 * 64);
    int*   selM = (int*)take((size_t)800 * 64);
    int*   flagsP = (int*)take(kNBLK);
    int*   slotsP = (int*)take(kNBLK);
    int*   ulist  = (int*)take(kNBLK);
    int*   bsum   = (int*)take(256);
    int*   mcount = (int*)take(16);
    int*   memfP  = (int*)take(1024);
    _Float16* W1h = takeh((size_t)512 * 768);
    _Float16* W1l = takeh((size_t)512 * 768);
    _Float16* W2h = takeh((size_t)256 * 512);
    _Float16* W2l = takeh((size_t)256 * 512);
    _Float16* BCh = takeh((size_t)512 * 256);
    _Float16* BCl = takeh((size_t)512 * 256);
    _Float16* ALh = takeh((size_t)256 * 256);
    _Float16* ALl = takeh((size_t)256 * 256);
    _Float16* WQh = takeh((size_t)256 * 256);
    _Float16* WQl = takeh((size_t)256 * 256);

    // 1) dedup pipeline + B-plane splits
    k_clear<<<dim3(256), dim3(256), 0, stream>>>(flagsP);
    k_mark <<<dim3(200), dim3(256), 0, stream>>>(in_txt, flagsP, 51200);
    k_scan_a<<<dim3(256), dim3(256), 0, stream>>>(flagsP, slotsP, bsum);
    k_scan_b<<<dim3(1),   dim3(256), 0, stream>>>(bsum, mcount);
    k_scan_c<<<dim3(256), dim3(256), 0, stream>>>(flagsP, slotsP, bsum, ulist);
    k_split_bT<<<dim3(512), dim3(256), 0, stream>>>(bt_w1, 512, 768, W1h, W1l, 0, 768, S12);
    k_split_bT<<<dim3(256), dim3(256), 0, stream>>>(bt_w2, 256, 512, W2h, W2l, 0, 512, S12);
    k_split_bT<<<dim3(256), dim3(256), 0, stream>>>(am_w1 + 256 * 256, 256, 256, BCh, BCl, 0,   256, S12);
    k_split_bT<<<dim3(256), dim3(256), 0, stream>>>(wk,                256, 256, BCh, BCl, 256, 256, S12);
    k_split_bT<<<dim3(256), dim3(256), 0, stream>>>(am_w1, 256, 256, ALh, ALl, 0, 256, S12);
    k_split_bT<<<dim3(256), dim3(256), 0, stream>>>(wq,    256, 256, WQh, WQl, 0, 256, S12);

    // 2) tvp = tva@am_w1_lo + am_b1 ; qw = (tva+v_all)@wq   (grid 14: fallback path)
    gemm_mfma3<<<dim3(14), dim3(256), 0, stream>>>(
        tva, 256, nullptr, nullptr, ALh, ALl, tvpP, 256,
        2, 800, nullptr, 256, am_b1, 0, S7, INV19);
    gemm_mfma3<<<dim3(14), dim3(256), 0, stream>>>(
        tva, 256, nullptr, v_all, WQh, WQl, qwP, 256,
        2, 800, nullptr, 256, nullptr, 0, S7, INV19);

    // 3) tables: H = relu(emb[ulist]@W1+b1) -> f32; Y = H@W2+b2 -> Tt; LN; AK
    gemm_mfma3<<<dim3(1600), dim3(256), 0, stream>>>(
        emb, 768, ulist, nullptr, W1h, W1l, Hp, 512,
        4, 0, mcount, 768, bt_b1, 1, S12, INV24);
    gemm_mfma3<<<dim3(800), dim3(256), 0, stream>>>(
        Hp, 512, nullptr, nullptr, W2h, W2l, Tt, 256,
        2, 0, mcount, 512, bt_b2, 0, S12, INV24);
    ln256_inplace<<<dim3(kMaxUsed), dim3(256), 0, stream>>>(Tt, bt_g, bt_bb, 0, mcount);
    gemm_mfma3<<<dim3(1600), dim3(256), 0, stream>>>(
        Tt, 256, nullptr, nullptr, BCh, BCl, AKp, 512,
        4, 0, mcount, 256, nullptr, 0, S8, INV20);

    // 4) phase-1 scores + stable full sort
    p1score<<<dim3(800), dim3(256), 0, stream>>>(tvpP, AKp, slotsP, am_w2, in_txt, scP);
    p1sort<<<dim3(800), dim3(64), 0, stream>>>(scP, in_txt, mk_txt, selI, selM);

    // 5) E table (overwrites Hp — Hp is dead after step 3's Y-GEMM)
    etab2<<<dim3(50, 16), dim3(256), 0, stream>>>(qwP, AKp, slotsP, selI, Ep);

    // 6) sequential recurrence -> memory_final (writes output 1)
    recur<<<dim3(16), dim3(64), 0, stream>>>(Ep, selI, selM, lens, memfP, dout + 32);

    // 7) pooling + output head (mem vectors gathered from T; writes output 0)
    head_k<<<dim3(16), dim3(256), 0, stream>>>(tva, lens, Tt, slotsP, memfP,
                                               out_w, out_b, dout);
}

// Round 15
// 571.707 us; speedup vs baseline: 1.2786x; 1.0727x over previous
//
#include <hip/hip_runtime.h>
#include <math.h>

// Problem constants
constexpr int kBS   = 16;
constexpr int kL    = 50;
constexpr int kNB   = 64;
constexpr int kD    = 256;
constexpr int kNBLK = 65536;
constexpr int kMaxUsed = 51200;          // 16*50*64 worst-case unique ids

#define NEG_HUGE (-3.402823466e38f)

typedef _Float16 h8 __attribute__((ext_vector_type(8)));
typedef _Float16 h4 __attribute__((ext_vector_type(4)));
typedef float f32x4 __attribute__((ext_vector_type(4)));

// ---------------- helpers ----------------
__device__ __forceinline__ unsigned f2sort(float f) {
    unsigned u = __float_as_uint(f);
    return (u & 0x80000000u) ? ~u : (u | 0x80000000u);   // monotone ascending map
}

// ---------------- dedup: flags -> exclusive scan -> compact ----------------
__global__ void k_clear(int* __restrict__ flags) {
    flags[blockIdx.x * 256 + threadIdx.x] = 0;
}
__global__ void k_mark(const int* __restrict__ ids, int* __restrict__ flags, int n) {
    int i = blockIdx.x * 256 + threadIdx.x;
    if (i < n) flags[ids[i]] = 1;
}
__global__ void k_scan_a(const int* __restrict__ flags, int* __restrict__ slots,
                         int* __restrict__ bsum) {
    int i = blockIdx.x * 256 + threadIdx.x;
    __shared__ int s[256];
    int v = flags[i];
    s[threadIdx.x] = v; __syncthreads();
    for (int o = 1; o < 256; o <<= 1) {
        int t2 = (threadIdx.x >= o) ? s[threadIdx.x - o] : 0;
        __syncthreads();
        s[threadIdx.x] += t2;
        __syncthreads();
    }
    slots[i] = s[threadIdx.x] - v;
    if (threadIdx.x == 255) bsum[blockIdx.x] = s[255];
}
__global__ void k_scan_b(int* __restrict__ bsum, int* __restrict__ mcount) {
    __shared__ int s[256];
    int v = bsum[threadIdx.x];
    s[threadIdx.x] = v; __syncthreads();
    for (int o = 1; o < 256; o <<= 1) {
        int t2 = (threadIdx.x >= o) ? s[threadIdx.x - o] : 0;
        __syncthreads();
        s[threadIdx.x] += t2;
        __syncthreads();
    }
    bsum[threadIdx.x] = s[threadIdx.x] - v;
    if (threadIdx.x == 255) *mcount = s[255];
}
__global__ void k_scan_c(const int* __restrict__ flags, int* __restrict__ slots,
                         const int* __restrict__ bsum, int* __restrict__ ulist) {
    int i = blockIdx.x * 256 + threadIdx.x;
    int slot = slots[i] + bsum[blockIdx.x];
    slots[i] = slot;
    if (flags[i]) ulist[slot] = i;
}

// ---------------- fused weight splits: all B planes in one dispatch ----------------
// Per-element math identical to the previous k_split_bT -> bitwise-identical planes.
__global__ void k_split_all(
    const float* __restrict__ bt_w1, const float* __restrict__ bt_w2,
    const float* __restrict__ am_w1, const float* __restrict__ wk,
    const float* __restrict__ wq,
    _Float16* __restrict__ W1h, _Float16* __restrict__ W1l,
    _Float16* __restrict__ W2h, _Float16* __restrict__ W2l,
    _Float16* __restrict__ BCh, _Float16* __restrict__ BCl,
    _Float16* __restrict__ ALh, _Float16* __restrict__ ALl,
    _Float16* __restrict__ WQh, _Float16* __restrict__ WQl,
    float scale)
{
    int b = blockIdx.x;
    const float* B; int ldb, K, n, row; _Float16 *Ph, *Pl; int ldp;
    if (b < 512)       { B = bt_w1;            ldb = 512; K = 768; n = b;        row = n;       Ph = W1h; Pl = W1l; ldp = 768; }
    else if (b < 768)  { B = bt_w2;            ldb = 256; K = 512; n = b - 512;  row = n;       Ph = W2h; Pl = W2l; ldp = 512; }
    else if (b < 1024) { B = am_w1 + 65536;    ldb = 256; K = 256; n = b - 768;  row = n;       Ph = BCh; Pl = BCl; ldp = 256; }
    else if (b < 1280) { B = wk;               ldb = 256; K = 256; n = b - 1024; row = n + 256; Ph = BCh; Pl = BCl; ldp = 256; }
    else if (b < 1536) { B = am_w1;            ldb = 256; K = 256; n = b - 1280; row = n;       Ph = ALh; Pl = ALl; ldp = 256; }
    else               { B = wq;               ldb = 256; K = 256; n = b - 1536; row = n;       Ph = WQh; Pl = WQl; ldp = 256; }
    for (int k = threadIdx.x; k < K; k += 256) {
        float v = B[(long long)k * ldb + n] * scale;
        _Float16 h = (_Float16)v;
        _Float16 l = (_Float16)(v - (float)h);
        Ph[(long long)row * ldp + k] = h;
        Pl[(long long)row * ldp + k] = l;
    }
}

// ---------------- split-f16 MFMA GEMM (round-8 config, best measured) ----------------
// C[M,N] = op( (A [+A2]) @ B * inv_scale + bias ), 3-product f16 split:
//   per element a*s rounded to ah+al (exact), b pre-split planes [N][K].
//   acc += mfma(ah,bh) + mfma(ah,bl) + mfma(al,bh)   (f32 accumulate)
// BM=BN=128, BK=32, 256 threads = 4 waves (2x2), per-wave 64x64 of 16x16x32 tiles.
__global__ __launch_bounds__(256) void gemm_mfma3(
    const float* __restrict__ A, int lda,
    const int* __restrict__ gather, const float* __restrict__ A2,
    const _Float16* __restrict__ Bh, const _Float16* __restrict__ Bl,
    float* __restrict__ C, int ldc,
    int Mstatic, const int* __restrict__ mcount,
    int K, const float* __restrict__ bias, int relu,
    float ascale, float inv_scale)
{
    int mlim = Mstatic;
    if (mcount) mlim = *mcount;
    const int bm = blockIdx.x * 128;
    if (bm >= mlim) return;
    const int bn = blockIdx.y * 128;

    __shared__ _Float16 Ash[128][40];
    __shared__ _Float16 Asl[128][40];
    __shared__ _Float16 Bsh[128][40];
    __shared__ _Float16 Bsl[128][40];

    const int t = threadIdx.x;

    const float* aptr[4];
    const float* aptr2[4];
    int arow[4], aoff[4];
    #pragma unroll
    for (int i = 0; i < 4; ++i) {
        int c = t + i * 256;
        int r = c >> 3, o = (c & 7) * 4;
        arow[i] = r; aoff[i] = o;
        int grow = bm + r;
        long long g = 0;
        if (grow < mlim) g = gather ? (long long)gather[grow] : (long long)grow;
        aptr[i]  = A + g * lda + o;
        aptr2[i] = A2 ? (A2 + g * lda + o) : nullptr;
    }
    const _Float16* bptr[4];
    int brow[4], boff[4], bpl[4];
    #pragma unroll
    for (int i = 0; i < 4; ++i) {
        int c = t + i * 256;
        int pl = c >> 9, cc = c & 511;
        int r = cc >> 2, o = (cc & 3) * 8;
        brow[i] = r; boff[i] = o; bpl[i] = pl;
        bptr[i] = (pl ? Bl : Bh) + (long long)(bn + r) * K + o;
    }

    f32x4 acc[4][4];
    #pragma unroll
    for (int m = 0; m < 4; ++m)
        #pragma unroll
        for (int n = 0; n < 4; ++n)
            acc[m][n] = (f32x4){0.f, 0.f, 0.f, 0.f};

    const int lane = t & 63;
    const int wid  = t >> 6;
    const int wr = (wid >> 1) * 64, wc = (wid & 1) * 64;
    const int fr = lane & 15, fk = (lane >> 4) * 8;

    float4 pa[4], pa2[4];
    h8 pb[4];
    #pragma unroll
    for (int i = 0; i < 4; ++i) {
        pa[i] = *(const float4*)(aptr[i]);
        if (A2) pa2[i] = *(const float4*)(aptr2[i]);
        pb[i] = *(const h8*)(bptr[i]);
    }

    const int nt = K / 32;
    for (int tI = 0; tI < nt; ++tI) {
        __syncthreads();
        #pragma unroll
        for (int i = 0; i < 4; ++i) {
            float vx = pa[i].x, vy = pa[i].y, vz = pa[i].z, vw = pa[i].w;
            if (A2) { vx += pa2[i].x; vy += pa2[i].y; vz += pa2[i].z; vw += pa2[i].w; }
            vx *= ascale; vy *= ascale; vz *= ascale; vw *= ascale;
            h4 hh, ll;
            hh[0] = (_Float16)vx; ll[0] = (_Float16)(vx - (float)hh[0]);
            hh[1] = (_Float16)vy; ll[1] = (_Float16)(vy - (float)hh[1]);
            hh[2] = (_Float16)vz; ll[2] = (_Float16)(vz - (float)hh[2]);
            hh[3] = (_Float16)vw; ll[3] = (_Float16)(vw - (float)hh[3]);
            *(h4*)&Ash[arow[i]][aoff[i]] = hh;
            *(h4*)&Asl[arow[i]][aoff[i]] = ll;
        }
        #pragma unroll
        for (int i = 0; i < 4; ++i) {
            _Float16* dst = bpl[i] ? &Bsl[brow[i]][boff[i]] : &Bsh[brow[i]][boff[i]];
            *(h8*)dst = pb[i];
        }
        __syncthreads();
        if (tI + 1 < nt) {
            int k0 = (tI + 1) * 32;
            #pragma unroll
            for (int i = 0; i < 4; ++i) {
                pa[i] = *(const float4*)(aptr[i] + k0);
                if (A2) pa2[i] = *(const float4*)(aptr2[i] + k0);
                pb[i] = *(const h8*)(bptr[i] + k0);
            }
        }
        h8 ah_[4], al_[4];
        #pragma unroll
        for (int m = 0; m < 4; ++m) {
            ah_[m] = *(const h8*)&Ash[wr + m * 16 + fr][fk];
            al_[m] = *(const h8*)&Asl[wr + m * 16 + fr][fk];
        }
        #pragma unroll
        for (int n = 0; n < 4; ++n) {
            h8 bh_ = *(const h8*)&Bsh[wc + n * 16 + fr][fk];
            h8 bl_ = *(const h8*)&Bsl[wc + n * 16 + fr][fk];
            #pragma unroll
            for (int m = 0; m < 4; ++m) {
                acc[m][n] = __builtin_amdgcn_mfma_f32_16x16x32_f16(ah_[m], bh_, acc[m][n], 0, 0, 0);
                acc[m][n] = __builtin_amdgcn_mfma_f32_16x16x32_f16(ah_[m], bl_, acc[m][n], 0, 0, 0);
                acc[m][n] = __builtin_amdgcn_mfma_f32_16x16x32_f16(al_[m], bh_, acc[m][n], 0, 0, 0);
            }
        }
    }

    // epilogue: C/D layout col=lane&15, row=(lane>>4)*4+reg
    const int cr0 = (lane >> 4) * 4;
    #pragma unroll
    for (int m = 0; m < 4; ++m) {
        #pragma unroll
        for (int r = 0; r < 4; ++r) {
            int row = bm + wr + m * 16 + cr0 + r;
            if (row >= mlim) continue;
            float* crow = C + (long long)row * ldc;
            #pragma unroll
            for (int n = 0; n < 4; ++n) {
                int col = bn + wc + n * 16 + fr;
                float v = acc[m][n][r] * inv_scale;
                if (bias) v += bias[col];
                if (relu) v = fmaxf(v, 0.f);
                crow[col] = v;
            }
        }
    }
}

// ---------------- in-place LayerNorm over rows of 256 ----------------
__global__ __launch_bounds__(256) void ln256_inplace(
    float* __restrict__ Y, const float* __restrict__ g, const float* __restrict__ b,
    int Mstatic, const int* __restrict__ mcount)
{
    int row = blockIdx.x;
    int mlim = mcount ? *mcount : Mstatic;
    if (row >= mlim) return;
    int d = threadIdx.x;
    float v = Y[(long long)row * 256 + d];
    __shared__ float red[256];
    red[d] = v; __syncthreads();
    for (int off = 128; off; off >>= 1) { if (d < off) red[d] += red[d + off]; __syncthreads(); }
    float mu = red[0] * (1.f / 256.f);
    __syncthreads();
    float dv = v - mu;
    red[d] = dv * dv; __syncthreads();
    for (int off = 128; off; off >>= 1) { if (d < off) red[d] += red[d + off]; __syncthreads(); }
    float var = red[0] * (1.f / 256.f);
    float out = g[d] * dv * (1.f / sqrtf(var + 1e-5f)) + b[d];
    Y[(long long)row * 256 + d] = out;
}

// ---------------- fused phase-1: scores + stable full sort in one kernel ----------------
// Scores computed exactly as before (same fp ops -> bitwise-identical keys),
// stored to LDS, then 64-wide bitonic with all 256 threads hitting barriers.
__global__ __launch_bounds__(256) void p1fused(
    const float* __restrict__ tvp, const float* __restrict__ AK,
    const int* __restrict__ slots, const float* __restrict__ am_w2,
    const int* __restrict__ ids, const int* __restrict__ mk_in,
    int* __restrict__ sel_ids, int* __restrict__ sel_mk)
{
    int bl = blockIdx.x;            // 0..799 == (b*50+l)
    int t = threadIdx.x;
    int lane = t & 63;
    int wv   = t >> 6;              // 0..3
    __shared__ float sc[64];
    __shared__ unsigned long long sk[64];

    float4 tv = *(const float4*)(tvp + (long long)bl * 256 + lane * 4);
    float4 w2 = *(const float4*)(am_w2 + lane * 4);
    for (int s = wv * 16; s < wv * 16 + 16; ++s) {
        int slot = slots[ids[bl * 64 + s]];
        float4 a = *(const float4*)(AK + (long long)slot * 512 + lane * 4);
        double p = (double)tanhf(tv.x + a.x) * w2.x
                 + (double)tanhf(tv.y + a.y) * w2.y
                 + (double)tanhf(tv.z + a.z) * w2.z
                 + (double)tanhf(tv.w + a.w) * w2.w;
        #pragma unroll
        for (int off = 32; off; off >>= 1) p += __shfl_down(p, off);
        if (lane == 0) sc[s] = (float)p;
    }
    __syncthreads();

    if (t < 64) {
        int mk = mk_in[bl * 64 + t];
        float key = mk ? sc[t] : NEG_HUGE;
        sk[t] = ((unsigned long long)(~f2sort(key)) << 32) | (unsigned)t;
    }
    // bitonic ascending sort of 64 keys; all 256 threads hit the barriers
    for (int k = 2; k <= 64; k <<= 1) {
        for (int j = k >> 1; j > 0; j >>= 1) {
            __syncthreads();
            if (t < 64) {
                int ixj = t ^ j;
                if (ixj > t) {
                    unsigned long long x = sk[t], y = sk[ixj];
                    bool sw = ((t & k) == 0) ? (x > y) : (x < y);
                    if (sw) { sk[t] = y; sk[ixj] = x; }
                }
            }
        }
    }
    __syncthreads();
    if (t < 64) {
        int src = (int)(unsigned)(sk[t] & 0xffffffffull);
        sel_ids[bl * 64 + t] = ids[bl * 64 + src];
        sel_mk [bl * 64 + t] = mk_in[bl * 64 + src];
    }
}

// ---------------- E table: tiled gather-GEMM over K-half of AK ----------------
__global__ __launch_bounds__(256) void etab2(
    const float* __restrict__ qw, const float* __restrict__ AK,
    const int* __restrict__ slots, const int* __restrict__ sel_ids,
    float* __restrict__ E)
{
    const int l = blockIdx.x;   // 0..49
    const int b = blockIdx.y;   // 0..15
    __shared__ float Ks[16][64];
    __shared__ float Qs[16][68];
    __shared__ int rowA[64];
    const int t  = threadIdx.x;
    const int tx = t & 15, ty = t >> 4;
    if (t < 64) rowA[t] = slots[sel_ids[(b * kL + l) * 64 + t]];
    __syncthreads();

    const int rA = t >> 2;          // 0..63
    const int kA = (t & 3) * 4;
    const float* aptr = AK + (long long)rowA[rA] * 512 + 256 + kA;
    const float* qbase = qw + ((long long)b * kL + 1) * 256;
    const bool tsok = rA < 49;

    double acc[4][4];
    #pragma unroll
    for (int i = 0; i < 4; ++i)
        #pragma unroll
        for (int j = 0; j < 4; ++j) acc[i][j] = 0.0;

    for (int k0 = 0; k0 < 256; k0 += 16) {
        float4 av = *(const float4*)(aptr + k0);
        float4 bv = make_float4(0.f, 0.f, 0.f, 0.f);
        if (tsok) bv = *(const float4*)(qbase + (long long)rA * 256 + k0 + kA);
        __syncthreads();
        Ks[kA + 0][rA] = av.x; Ks[kA + 1][rA] = av.y;
        Ks[kA + 2][rA] = av.z; Ks[kA + 3][rA] = av.w;
        Qs[kA + 0][rA] = bv.x; Qs[kA + 1][rA] = bv.y;
        Qs[kA + 2][rA] = bv.z; Qs[kA + 3][rA] = bv.w;
        __syncthreads();
        #pragma unroll
        for (int k = 0; k < 16; ++k) {
            float a[4], q[4];
            *(float4*)&a[0] = *(const float4*)&Ks[k][tx * 4];
            *(float4*)&q[0] = *(const float4*)&Qs[k][ty * 4];
            #pragma unroll
            for (int i = 0; i < 4; ++i)
                #pragma unroll
                for (int j = 0; j < 4; ++j)
                    acc[i][j] += (double)a[i] * (double)q[j];
        }
    }
    #pragma unroll
    for (int j = 0; j < 4; ++j) {
        int ts = ty * 4 + j;
        if (ts >= 49) continue;
        #pragma unroll
        for (int i = 0; i < 4; ++i) {
            int s = tx * 4 + i;
            E[((long long)b * 49 + ts) * 3200 + l * 64 + s] = (float)acc[i][j];
        }
    }
}

// ---------------- sequential memory recurrence: 1 wave/batch, register bitonic ----------------
__global__ __launch_bounds__(64) void recur(
    const float* __restrict__ E, const int* __restrict__ sel_ids,
    const int* __restrict__ sel_mk, const int* __restrict__ lengths,
    int* __restrict__ memf, float* __restrict__ dout_mem)
{
    const int b = blockIdx.x;
    const int lane = threadIdx.x;

    int cid = sel_ids[(b * kL) * 64 + lane];
    int cmk = sel_mk [(b * kL) * 64 + lane];
    int ccd = lane;

    const int tlast = lengths[b] - 2;           // in [0,48]
    const float* Eb = E + (long long)b * 49 * 3200;

    for (int ts = 0; ts <= tlast; ++ts) {
        int nid = sel_ids[(b * kL + ts + 1) * 64 + lane];
        int nmk = sel_mk [(b * kL + ts + 1) * 64 + lane];
        const float* Et = Eb + (long long)ts * 3200;

        float k0 = cmk ? Et[ccd] : NEG_HUGE;
        float k1 = nmk ? Et[(ts + 1) * 64 + lane] : NEG_HUGE;
        unsigned long long s0 = ((unsigned long long)(~f2sort(k0)) << 32) | (unsigned)lane;
        unsigned long long s1 = ((unsigned long long)(~f2sort(k1)) << 32) | (unsigned)(64 + lane);

        #pragma unroll
        for (int k = 2; k <= 128; k <<= 1) {
            #pragma unroll
            for (int j = k >> 1; j > 0; j >>= 1) {
                if (j == 64) {
                    unsigned long long mn = s0 < s1 ? s0 : s1;
                    unsigned long long mx = s0 < s1 ? s1 : s0;
                    s0 = mn; s1 = mx;
                } else {
                    bool up   = (lane & j) == 0;
                    bool asc0 = (lane & k) == 0;
                    bool asc1 = (((lane + 64) & k) == 0);
                    unsigned long long p0 = __shfl_xor(s0, j, 64);
                    unsigned long long p1 = __shfl_xor(s1, j, 64);
                    bool km0 = (asc0 == up), km1 = (asc1 == up);
                    s0 = (km0 == (s0 < p0)) ? s0 : p0;
                    s1 = (km1 == (s1 < p1)) ? s1 : p1;
                }
            }
        }

        int src  = (int)(unsigned)(s0 & 0xffffffffull);
        int srcl = src & 63;
        int c_id = __shfl(cid, srcl, 64);
        int c_mk = __shfl(cmk, srcl, 64);
        int c_cd = __shfl(ccd, srcl, 64);
        int n_id = __shfl(nid, srcl, 64);
        int n_mk = __shfl(nmk, srcl, 64);
        bool isnew = src >= 64;
        cid = isnew ? n_id : c_id;
        cmk = isnew ? n_mk : c_mk;
        ccd = isnew ? ((ts + 1) * 64 + srcl) : c_cd;
    }

    memf[b * 64 + lane] = cid;
    dout_mem[b * 64 + lane] = (float)cid;
}

// ---------------- final pooling + output head (mem rows gathered from T) ----------------
__global__ __launch_bounds__(256) void head_k(
    const float* __restrict__ tva, const int* __restrict__ lengths,
    const float* __restrict__ T, const int* __restrict__ slots,
    const int* __restrict__ memf, const float* __restrict__ out_w,
    const float* __restrict__ out_b, float* __restrict__ dout)
{
    int b = blockIdx.x, d = threadIdx.x;
    int len = lengths[b];
    float vf = NEG_HUGE;
    for (int l = 0; l < len; ++l) vf = fmaxf(vf, tva[((long long)b * kL + l) * 256 + d]);
    float mv = NEG_HUGE;
    for (int m = 0; m < 64; ++m) {
        int slot = slots[memf[b * 64 + m]];
        mv = fmaxf(mv, T[(long long)slot * 256 + d]);
    }
    double p0 = (double)vf * out_w[d * 2 + 0] + (double)mv * out_w[(256 + d) * 2 + 0];
    double p1 = (double)vf * out_w[d * 2 + 1] + (double)mv * out_w[(256 + d) * 2 + 1];
    __shared__ double r0[256], r1[256];
    r0[d] = p0; r1[d] = p1; __syncthreads();
    for (int off = 128; off; off >>= 1) {
        if (d < off) { r0[d] += r0[d + off]; r1[d] += r1[d + off]; }
        __syncthreads();
    }
    if (d == 0) {
        dout[b * 2 + 0] = (float)(r0[0] + out_b[0]);
        dout[b * 2 + 1] = (float)(r1[0] + out_b[1]);
    }
}

// ---------------- host orchestration ----------------
extern "C" void kernel_launch(void* const* d_in, const int* in_sizes, int n_in,
                              void* d_out, int out_size, void* d_ws, size_t ws_size,
                              hipStream_t stream)
{
    const float* v_all  = (const float*)d_in[0];
    const float* tva    = (const float*)d_in[1];
    const float* emb    = (const float*)d_in[2];
    const float* bt_w1  = (const float*)d_in[3];
    const float* bt_b1  = (const float*)d_in[4];
    const float* bt_w2  = (const float*)d_in[5];
    const float* bt_b2  = (const float*)d_in[6];
    const float* bt_g   = (const float*)d_in[7];
    const float* bt_bb  = (const float*)d_in[8];
    const float* wq     = (const float*)d_in[9];
    const float* wk     = (const float*)d_in[10];
    const float* am_w1  = (const float*)d_in[11];
    const float* am_b1  = (const float*)d_in[12];
    const float* am_w2  = (const float*)d_in[13];
    const float* out_w  = (const float*)d_in[14];
    const float* out_b  = (const float*)d_in[15];
    const int*   in_txt = (const int*)d_in[16];
    const int*   mk_txt = (const int*)d_in[17];
    const int*   lens   = (const int*)d_in[18];
    float* dout = (float*)d_out;

    const float S12 = 4096.f, S7 = 128.f, S8 = 256.f;
    const float INV24 = 1.f / 16777216.f;   // 2^-24
    const float INV19 = 1.f / 524288.f;     // 2^-19
    const float INV20 = 1.f / 1048576.f;    // 2^-20

    size_t off = 0;
    float* W = (float*)d_ws;
    auto take = [&](size_t n) { float* p = W + off; off += (n + 3) & ~(size_t)3; return p; };
    auto takeh = [&](size_t nh) { return (_Float16*)take((nh + 1) / 2); };

    float* AKp  = take((size_t)kMaxUsed * 512);
    float* Tt   = take((size_t)kMaxUsed * 256);
    float* Hp   = take((size_t)kMaxUsed * 512);
    float* Ep   = Hp;                                   // alias: E used after Hp is dead
    float* tvpP = take((size_t)800 * 256);
    float* qwP  = take((size_t)800 * 256);
    int*   selI = (int*)take((size_t)800 * 64);
    int*   selM = (int*)take((size_t)800 * 64);
    int*   flagsP = (int*)take(kNBLK);
    int*   slotsP = (int*)take(kNBLK);
    int*   ulist  = (int*)take(kNBLK);
    int*   bsum   = (int*)take(256);
    int*   mcount = (int*)take(16);
    int*   memfP  = (int*)take(1024);
    _Float16* W1h = takeh((size_t)512 * 768);
    _Float16* W1l = takeh((size_t)512 * 768);
    _Float16* W2h = takeh((size_t)256 * 512);
    _Float16* W2l = takeh((size_t)256 * 512);
    _Float16* BCh = takeh((size_t)512 * 256);
    _Float16* BCl = takeh((size_t)512 * 256);
    _Float16* ALh = takeh((size_t)256 * 256);
    _Float16* ALl = takeh((size_t)256 * 256);
    _Float16* WQh = takeh((size_t)256 * 256);
    _Float16* WQl = takeh((size_t)256 * 256);

    // 1) dedup pipeline + fused B-plane splits
    k_clear<<<dim3(256), dim3(256), 0, stream>>>(flagsP);
    k_mark <<<dim3(200), dim3(256), 0, stream>>>(in_txt, flagsP, 51200);
    k_scan_a<<<dim3(256), dim3(256), 0, stream>>>(flagsP, slotsP, bsum);
    k_scan_b<<<dim3(1),   dim3(256), 0, stream>>>(bsum, mcount);
    k_scan_c<<<dim3(256), dim3(256), 0, stream>>>(flagsP, slotsP, bsum, ulist);
    k_split_all<<<dim3(1792), dim3(256), 0, stream>>>(
        bt_w1, bt_w2, am_w1, wk, wq,
        W1h, W1l, W2h, W2l, BCh, BCl, ALh, ALl, WQh, WQl, S12);

    // 2) tvp = tva@am_w1_lo + am_b1 ; qw = (tva+v_all)@wq
    gemm_mfma3<<<dim3(7, 2), dim3(256), 0, stream>>>(
        tva, 256, nullptr, nullptr, ALh, ALl, tvpP, 256, 800, nullptr, 256, am_b1, 0, S7, INV19);
    gemm_mfma3<<<dim3(7, 2), dim3(256), 0, stream>>>(
        tva, 256, nullptr, v_all, WQh, WQl, qwP, 256, 800, nullptr, 256, nullptr, 0, S7, INV19);

    // 3) tables: H = relu(emb[ulist]@W1+b1); Tpre = H@W2+b2; LN; AK = T@[Ahi|wk]
    gemm_mfma3<<<dim3(kMaxUsed / 128, 4), dim3(256), 0, stream>>>(
        emb, 768, ulist, nullptr, W1h, W1l, Hp, 512, 0, mcount, 768, bt_b1, 1, S12, INV24);
    gemm_mfma3<<<dim3(kMaxUsed / 128, 2), dim3(256), 0, stream>>>(
        Hp, 512, nullptr, nullptr, W2h, W2l, Tt, 256, 0, mcount, 512, bt_b2, 0, S12, INV24);
    ln256_inplace<<<dim3(kMaxUsed), dim3(256), 0, stream>>>(Tt, bt_g, bt_bb, 0, mcount);
    gemm_mfma3<<<dim3(kMaxUsed / 128, 4), dim3(256), 0, stream>>>(
        Tt, 256, nullptr, nullptr, BCh, BCl, AKp, 512, 0, mcount, 256, nullptr, 0, S8, INV20);

    // 4) phase-1 scores + stable full sort (fused)
    p1fused<<<dim3(800), dim3(256), 0, stream>>>(
        tvpP, AKp, slotsP, am_w2, in_txt, mk_txt, selI, selM);

    // 5) E table (overwrites Hp — Hp is dead after step 3's Y-GEMM)
    etab2<<<dim3(50, 16), dim3(256), 0, stream>>>(qwP, AKp, slotsP, selI, Ep);

    // 6) sequential recurrence -> memory_final (writes output 1)
    recur<<<dim3(16), dim3(64), 0, stream>>>(Ep, selI, selM, lens, memfP, dout + 32);

    // 7) pooling + output head (mem vectors gathered from T; writes output 0)
    head_k<<<dim3(16), dim3(256), 0, stream>>>(tva, lens, Tt, slotsP, memfP,
                                               out_w, out_b, dout);
}